// Round 1
// baseline (612.194 us; speedup 1.0000x reference)
//
#include <hip/hip_runtime.h>
#include <math.h>

// Problem constants
constexpr int BB   = 16;
constexpr int NPGc = 4096;
constexpr int Cc   = 256;
constexpr int Nc   = BB * NPGc;      // 65536
constexpr int Ec   = Nc * 16;        // 1048576 = 1<<20
constexpr int Kc   = 1024;           // ceil(0.25*4096)

// ---------- monotonic double <-> u64 key ----------
__device__ __forceinline__ unsigned long long dkey(double f) {
    long long b = __double_as_longlong(f);
    unsigned long long u = (unsigned long long)b;
    return (b < 0) ? ~u : (u | 0x8000000000000000ULL);
}
__device__ __forceinline__ double inv_dkey(unsigned long long u) {
    unsigned long long b = (u & 0x8000000000000000ULL) ? (u ^ 0x8000000000000000ULL) : ~u;
    return __longlong_as_double((long long)b);
}

// ---------- kernel 1: kqv = x @ w + b for both node sets ----------
// one wave per row; lane loads float4 of x (16B/lane coalesced) and the
// matching 12 floats of w (3KB, L1-resident broadcast); fp64 accumulate.
__global__ __launch_bounds__(256) void kqv_kernel(
    const float* __restrict__ x_inst, const float* __restrict__ x_data,
    const float* __restrict__ w_inst, const float* __restrict__ b_inst,
    const float* __restrict__ w_data, const float* __restrict__ b_data,
    double* __restrict__ k_i, double* __restrict__ v_i,
    double* __restrict__ k_d, double* __restrict__ v_d,
    double* __restrict__ q_glob)
{
    int row  = (blockIdx.x * blockDim.x + threadIdx.x) >> 6;   // 0..2N-1
    int lane = threadIdx.x & 63;
    int side = (row >= Nc) ? 1 : 0;
    int node = row - side * Nc;
    const float* x  = side ? x_data : x_inst;
    const float* w  = side ? w_data : w_inst;
    const float* bb = side ? b_data : b_inst;

    float4 xv = ((const float4*)(x + (size_t)node * Cc))[lane];
    const float* wp = w + lane * 12;   // rows 4*lane..4*lane+3, 3 cols each
    float xs[4] = {xv.x, xv.y, xv.z, xv.w};
    double kk = 0.0, qq = 0.0, vv = 0.0;
#pragma unroll
    for (int u = 0; u < 4; ++u) {
        double xd = (double)xs[u];
        kk += xd * (double)wp[u * 3 + 0];
        qq += xd * (double)wp[u * 3 + 1];
        vv += xd * (double)wp[u * 3 + 2];
    }
#pragma unroll
    for (int off = 32; off; off >>= 1) {
        kk += __shfl_down(kk, off, 64);
        qq += __shfl_down(qq, off, 64);
        vv += __shfl_down(vv, off, 64);
    }
    if (lane == 0) {
        kk += (double)bb[0]; qq += (double)bb[1]; vv += (double)bb[2];
        if (side) { k_d[node] = kk; v_d[node] = vv; q_glob[Nc + node] = qq; }
        else      { k_i[node] = kk; v_i[node] = vv; q_glob[node]      = qq; }
    }
}

// ---------- kernel 2: single-pass edge softmax sums ----------
// No segment-max needed: fp64 exp has huge range (|logit| <~ 50 here), and
// a = sum(e^l * v)/sum(e^l) is invariant to the max shift the reference does.
__global__ __launch_bounds__(256) void edge_kernel(
    const int* __restrict__ ei0, const int* __restrict__ ei1,
    const int* __restrict__ ei2,
    const float* __restrict__ krel_w, const float* __restrict__ krel_b,
    const float* __restrict__ vrel_w, const float* __restrict__ vrel_b,
    const float* __restrict__ p_rel,
    const double* __restrict__ k_i, const double* __restrict__ v_i,
    const double* __restrict__ k_d, const double* __restrict__ v_d,
    const double* __restrict__ q_glob,
    double* __restrict__ den, double* __restrict__ num)
{
    unsigned gid = blockIdx.x * 256u + threadIdx.x;
    int t = (int)(gid >> 20);              // uniform per block (E = 1<<20)
    int i = (int)(gid & (unsigned)(Ec - 1));
    const int*    ei = (t == 0) ? ei0 : (t == 1) ? ei1 : ei2;
    const double* ks = (t == 1) ? k_d : k_i;
    const double* vs = (t == 1) ? v_d : v_i;
    int off = (t == 0) ? Nc : 0;

    int s = ei[i];
    int d = ei[Ec + i];
    double ke = ks[s] * (double)krel_w[t] + (double)krel_b[t];
    double ve = vs[s] * (double)vrel_w[t] + (double)vrel_b[t];
    int dg = d + off;
    double logit = q_glob[dg] * ke * (double)p_rel[t];
    double ex = exp(logit);
    atomicAdd(&den[dg], ex);
    atomicAdd(&num[dg], ex * ve);
}

// ---------- kernel 3: gelu score + radix top-K select per (side,batch) ----------
__global__ __launch_bounds__(256) void select_kernel(
    const double* __restrict__ den, const double* __restrict__ num,
    const float* __restrict__ w_out_inst, const float* __restrict__ b_out_inst,
    const float* __restrict__ w_out_data, const float* __restrict__ b_out_data,
    int* __restrict__ sel_idx, float* __restrict__ sel_w)
{
    __shared__ unsigned long long keys[NPGc];   // 32 KB
    __shared__ unsigned hist[256];
    __shared__ unsigned sh_chosen, sh_rem, sh_cnt, sh_tiecnt;
    __shared__ int tie_idx[256];

    int tid  = threadIdx.x;
    int seg  = blockIdx.x;          // 0..31
    int side = seg >> 4;
    int b    = seg & 15;
    double wo = side ? (double)w_out_data[0] : (double)w_out_inst[0];
    double bo = side ? (double)b_out_data[0] : (double)b_out_inst[0];
    int base_node = side * Nc + b * NPGc;

    for (int ii = 0; ii < 16; ++ii) {
        int j = ii * 256 + tid;
        double dn = den[base_node + j];
        double a  = (dn > 0.0) ? num[base_node + j] / dn : 0.0;
        double z  = a * wo + bo;
        double s  = 0.5 * z * (1.0 + erf(z * 0.7071067811865476));  // exact gelu
        keys[j] = dkey(s);
    }
    if (tid == 0) { sh_rem = Kc; sh_cnt = 0; sh_tiecnt = 0; }
    __syncthreads();

    unsigned long long prefix = 0ULL;
    for (int p = 7; p >= 0; --p) {
        hist[tid] = 0;
        __syncthreads();
        for (int ii = 0; ii < 16; ++ii) {
            unsigned long long k64 = keys[ii * 256 + tid];
            bool cand = (p == 7) || ((k64 >> ((p + 1) * 8)) == prefix);
            if (cand) atomicAdd(&hist[(unsigned)(k64 >> (p * 8)) & 255u], 1u);
        }
        __syncthreads();
        if (tid == 0) {
            unsigned cum = 0; unsigned chosen = 0;
            for (int bb2 = 255; bb2 >= 0; --bb2) {
                unsigned c = hist[bb2];
                if (cum + c >= sh_rem) { chosen = (unsigned)bb2; sh_rem -= cum; break; }
                cum += c;
            }
            sh_chosen = chosen;
        }
        __syncthreads();
        prefix = (prefix << 8) | (unsigned long long)sh_chosen;
    }
    unsigned long long T = prefix;     // exact key of the K-th largest
    unsigned rem = sh_rem;             // #ties at T to take (lowest index first)

    int base_sel = seg * Kc;
    for (int ii = 0; ii < 16; ++ii) {
        int j = ii * 256 + tid;
        unsigned long long k64 = keys[j];
        if (k64 > T) {
            unsigned pos = atomicAdd(&sh_cnt, 1u);
            sel_idx[base_sel + pos] = j;
            sel_w[base_sel + pos]   = (float)tanh(inv_dkey(k64));
        } else if (k64 == T) {
            unsigned tp = atomicAdd(&sh_tiecnt, 1u);
            if (tp < 256u) tie_idx[tp] = j;
        }
    }
    __syncthreads();
    unsigned tc = min(sh_tiecnt, 256u);
    float wT = (float)tanh(inv_dkey(T));
    if (tid < (int)tc) {
        int myj = tie_idx[tid];
        unsigned rank = 0;
        for (unsigned q = 0; q < tc; ++q) rank += (tie_idx[q] < myj) ? 1u : 0u;
        if (rank < rem) {
            unsigned pos = atomicAdd(&sh_cnt, 1u);
            sel_idx[base_sel + pos] = myj;
            sel_w[base_sel + pos]   = wT;
        }
    }
}

// ---------- kernel 4: weighted mean of selected x rows ----------
// 32 segments x 32 chunks = 1024 blocks; thread = column; 32 rows/block.
__global__ __launch_bounds__(256) void pool_kernel(
    const float* __restrict__ x_inst, const float* __restrict__ x_data,
    const int* __restrict__ sel_idx, const float* __restrict__ sel_w,
    float* __restrict__ out)
{
    __shared__ int   ridx[32];
    __shared__ float rw[32];
    int tid   = threadIdx.x;
    int seg   = blockIdx.x >> 5;
    int chunk = blockIdx.x & 31;
    int side  = seg >> 4;
    int b     = seg & 15;
    int base_sel = seg * Kc + chunk * 32;
    if (tid < 32) { ridx[tid] = sel_idx[base_sel + tid]; rw[tid] = sel_w[base_sel + tid]; }
    __syncthreads();
    const float* x = side ? x_data : x_inst;
    float acc = 0.0f;
#pragma unroll
    for (int r = 0; r < 32; ++r) {
        acc += x[((size_t)(b * NPGc + ridx[r])) * Cc + tid] * rw[r];
    }
    atomicAdd(&out[b * 512 + side * 256 + tid], acc * (1.0f / (float)Kc));
}

extern "C" void kernel_launch(void* const* d_in, const int* in_sizes, int n_in,
                              void* d_out, int out_size, void* d_ws, size_t ws_size,
                              hipStream_t stream) {
    const float* x_inst     = (const float*)d_in[0];
    const float* x_data     = (const float*)d_in[1];
    const float* w_kqv_inst = (const float*)d_in[2];
    const float* b_kqv_inst = (const float*)d_in[3];
    const float* w_kqv_data = (const float*)d_in[4];
    const float* b_kqv_data = (const float*)d_in[5];
    const float* w_out_inst = (const float*)d_in[6];
    const float* b_out_inst = (const float*)d_in[7];
    const float* w_out_data = (const float*)d_in[8];
    const float* b_out_data = (const float*)d_in[9];
    const float* krel_w     = (const float*)d_in[10];
    const float* krel_b     = (const float*)d_in[11];
    const float* vrel_w     = (const float*)d_in[12];
    const float* vrel_b     = (const float*)d_in[13];
    const float* p_rel      = (const float*)d_in[14];
    const int*   ei_i2d     = (const int*)d_in[15];
    const int*   ei_d2i     = (const int*)d_in[16];
    const int*   ei_i2i     = (const int*)d_in[17];
    float* out = (float*)d_out;

    // workspace layout (bytes)
    char* ws = (char*)d_ws;
    double* k_i    = (double*)ws;                        // N
    double* v_i    = k_i + Nc;                           // N
    double* k_d    = v_i + Nc;                           // N
    double* v_d    = k_d + Nc;                           // N
    double* q_glob = v_d + Nc;                           // 2N
    size_t off_den = (size_t)6 * Nc * sizeof(double);    // 3,145,728
    double* den    = (double*)(ws + off_den);            // 2N
    double* num    = den + 2 * Nc;                       // 2N
    size_t off_sel = off_den + (size_t)4 * Nc * sizeof(double);
    int*   sel_idx = (int*)(ws + off_sel);               // 32*K
    float* sel_w   = (float*)(ws + off_sel + 32 * Kc * sizeof(int));

    // zero the atomic accumulators and the output
    hipMemsetAsync(ws + off_den, 0, (size_t)4 * Nc * sizeof(double), stream);
    hipMemsetAsync(d_out, 0, (size_t)out_size * sizeof(float), stream);

    // 1) kqv for both sides: 2N rows, 1 wave/row, 4 waves/block
    kqv_kernel<<<(2 * Nc) / 4, 256, 0, stream>>>(
        x_inst, x_data, w_kqv_inst, b_kqv_inst, w_kqv_data, b_kqv_data,
        k_i, v_i, k_d, v_d, q_glob);

    // 2) edge pass: 3E threads
    edge_kernel<<<(3 * Ec) / 256, 256, 0, stream>>>(
        ei_i2d, ei_d2i, ei_i2i, krel_w, krel_b, vrel_w, vrel_b, p_rel,
        k_i, v_i, k_d, v_d, q_glob, den, num);

    // 3) score + top-K select: one block per (side,batch)
    select_kernel<<<32, 256, 0, stream>>>(
        den, num, w_out_inst, b_out_inst, w_out_data, b_out_data,
        sel_idx, sel_w);

    // 4) pooled weighted mean
    pool_kernel<<<1024, 256, 0, stream>>>(x_inst, x_data, sel_idx, sel_w, out);
}

// Round 2
// 525.673 us; speedup vs baseline: 1.1646x; 1.1646x over previous
//
#include <hip/hip_runtime.h>
#include <math.h>

// Problem constants
constexpr int BB   = 16;
constexpr int NPGc = 4096;
constexpr int Cc   = 256;
constexpr int Nc   = BB * NPGc;      // 65536
constexpr int Ec   = Nc * 16;        // 1048576 = 1<<20
constexpr int Kc   = 1024;           // ceil(0.25*4096)

// ---------- monotonic double <-> u64 key ----------
__device__ __forceinline__ unsigned long long dkey(double f) {
    long long b = __double_as_longlong(f);
    unsigned long long u = (unsigned long long)b;
    return (b < 0) ? ~u : (u | 0x8000000000000000ULL);
}
__device__ __forceinline__ double inv_dkey(unsigned long long u) {
    unsigned long long b = (u & 0x8000000000000000ULL) ? (u ^ 0x8000000000000000ULL) : ~u;
    return __longlong_as_double((long long)b);
}

// ---------- kernel 1: kqv = x @ w + b for both node sets ----------
// one wave per row; lane loads float4 of x (16B/lane coalesced) and the
// matching 12 floats of w (3KB, L1-resident broadcast); fp64 accumulate.
__global__ __launch_bounds__(256) void kqv_kernel(
    const float* __restrict__ x_inst, const float* __restrict__ x_data,
    const float* __restrict__ w_inst, const float* __restrict__ b_inst,
    const float* __restrict__ w_data, const float* __restrict__ b_data,
    double* __restrict__ k_i, double* __restrict__ v_i,
    double* __restrict__ k_d, double* __restrict__ v_d,
    double* __restrict__ q_glob)
{
    int row  = (blockIdx.x * blockDim.x + threadIdx.x) >> 6;   // 0..2N-1
    int lane = threadIdx.x & 63;
    int side = (row >= Nc) ? 1 : 0;
    int node = row - side * Nc;
    const float* x  = side ? x_data : x_inst;
    const float* w  = side ? w_data : w_inst;
    const float* bb = side ? b_data : b_inst;

    float4 xv = ((const float4*)(x + (size_t)node * Cc))[lane];
    const float* wp = w + lane * 12;   // rows 4*lane..4*lane+3, 3 cols each
    float xs[4] = {xv.x, xv.y, xv.z, xv.w};
    double kk = 0.0, qq = 0.0, vv = 0.0;
#pragma unroll
    for (int u = 0; u < 4; ++u) {
        double xd = (double)xs[u];
        kk += xd * (double)wp[u * 3 + 0];
        qq += xd * (double)wp[u * 3 + 1];
        vv += xd * (double)wp[u * 3 + 2];
    }
#pragma unroll
    for (int off = 32; off; off >>= 1) {
        kk += __shfl_down(kk, off, 64);
        qq += __shfl_down(qq, off, 64);
        vv += __shfl_down(vv, off, 64);
    }
    if (lane == 0) {
        kk += (double)bb[0]; qq += (double)bb[1]; vv += (double)bb[2];
        if (side) { k_d[node] = kk; v_d[node] = vv; q_glob[Nc + node] = qq; }
        else      { k_i[node] = kk; v_i[node] = vv; q_glob[node]      = qq; }
    }
}

// ---------- kernel 2: single-pass edge softmax sums ----------
// No segment-max needed: fp64 exp has huge range (|logit| <~ 50 here), and
// a = sum(e^l * v)/sum(e^l) is invariant to the max shift the reference does.
// unsafeAtomicAdd -> native global_atomic_add_f64 (fire-and-forget), NOT the
// CAS loop the default atomicAdd lowers to without -munsafe-fp-atomics.
__global__ __launch_bounds__(256) void edge_kernel(
    const int* __restrict__ ei0, const int* __restrict__ ei1,
    const int* __restrict__ ei2,
    const float* __restrict__ krel_w, const float* __restrict__ krel_b,
    const float* __restrict__ vrel_w, const float* __restrict__ vrel_b,
    const float* __restrict__ p_rel,
    const double* __restrict__ k_i, const double* __restrict__ v_i,
    const double* __restrict__ k_d, const double* __restrict__ v_d,
    const double* __restrict__ q_glob,
    double* __restrict__ den, double* __restrict__ num)
{
    unsigned gid = blockIdx.x * 256u + threadIdx.x;
    int t = (int)(gid >> 20);              // uniform per block (E = 1<<20)
    int i = (int)(gid & (unsigned)(Ec - 1));
    const int*    ei = (t == 0) ? ei0 : (t == 1) ? ei1 : ei2;
    const double* ks = (t == 1) ? k_d : k_i;
    const double* vs = (t == 1) ? v_d : v_i;
    int off = (t == 0) ? Nc : 0;

    int s = ei[i];
    int d = ei[Ec + i];
    double ke = ks[s] * (double)krel_w[t] + (double)krel_b[t];
    double ve = vs[s] * (double)vrel_w[t] + (double)vrel_b[t];
    int dg = d + off;
    double logit = q_glob[dg] * ke * (double)p_rel[t];
    double ex = exp(logit);
    unsafeAtomicAdd(&den[dg], ex);
    unsafeAtomicAdd(&num[dg], ex * ve);
}

// ---------- kernel 3: gelu score + radix top-K select per (side,batch) ----------
__global__ __launch_bounds__(256) void select_kernel(
    const double* __restrict__ den, const double* __restrict__ num,
    const float* __restrict__ w_out_inst, const float* __restrict__ b_out_inst,
    const float* __restrict__ w_out_data, const float* __restrict__ b_out_data,
    int* __restrict__ sel_idx, float* __restrict__ sel_w)
{
    __shared__ unsigned long long keys[NPGc];   // 32 KB
    __shared__ unsigned hist[256];
    __shared__ unsigned suf[256];
    __shared__ unsigned sh_chosen, sh_rem, sh_rem2, sh_cnt, sh_tiecnt;
    __shared__ int tie_idx[256];

    int tid  = threadIdx.x;
    int seg  = blockIdx.x;          // 0..31
    int side = seg >> 4;
    int b    = seg & 15;
    double wo = side ? (double)w_out_data[0] : (double)w_out_inst[0];
    double bo = side ? (double)b_out_data[0] : (double)b_out_inst[0];
    int base_node = side * Nc + b * NPGc;

    for (int ii = 0; ii < 16; ++ii) {
        int j = ii * 256 + tid;
        double dn = den[base_node + j];
        double a  = (dn > 0.0) ? num[base_node + j] / dn : 0.0;
        double z  = a * wo + bo;
        double s  = 0.5 * z * (1.0 + erf(z * 0.7071067811865476));  // exact gelu
        keys[j] = dkey(s);
    }
    if (tid == 0) { sh_rem = Kc; sh_cnt = 0; sh_tiecnt = 0; }
    __syncthreads();

    unsigned long long prefix = 0ULL;
    for (int p = 7; p >= 0; --p) {
        hist[tid] = 0;
        __syncthreads();
        for (int ii = 0; ii < 16; ++ii) {
            unsigned long long k64 = keys[ii * 256 + tid];
            bool cand = (p == 7) || ((k64 >> ((p + 1) * 8)) == prefix);
            if (cand) atomicAdd(&hist[(unsigned)(k64 >> (p * 8)) & 255u], 1u);
        }
        __syncthreads();
        // parallel suffix-sum: suf[b] = sum_{j>=b} hist[j]
        suf[tid] = hist[tid];
        __syncthreads();
        for (int ofs = 1; ofs < 256; ofs <<= 1) {
            unsigned add = (tid + ofs < 256) ? suf[tid + ofs] : 0u;
            __syncthreads();
            suf[tid] += add;
            __syncthreads();
        }
        // unique bin b with suf[b] >= rem and suf[b+1] < rem
        unsigned below = (tid == 255) ? 0u : suf[tid + 1];
        if (suf[tid] >= sh_rem && below < sh_rem) {
            sh_chosen = (unsigned)tid;
            sh_rem2   = sh_rem - below;
        }
        __syncthreads();
        if (tid == 0) sh_rem = sh_rem2;
        __syncthreads();
        prefix = (prefix << 8) | (unsigned long long)sh_chosen;
    }
    unsigned long long T = prefix;     // exact key of the K-th largest
    unsigned rem = sh_rem;             // #ties at T to take (lowest index first)

    int base_sel = seg * Kc;
    for (int ii = 0; ii < 16; ++ii) {
        int j = ii * 256 + tid;
        unsigned long long k64 = keys[j];
        if (k64 > T) {
            unsigned pos = atomicAdd(&sh_cnt, 1u);
            sel_idx[base_sel + pos] = j;
            sel_w[base_sel + pos]   = (float)tanh(inv_dkey(k64));
        } else if (k64 == T) {
            unsigned tp = atomicAdd(&sh_tiecnt, 1u);
            if (tp < 256u) tie_idx[tp] = j;
        }
    }
    __syncthreads();
    unsigned tc = min(sh_tiecnt, 256u);
    float wT = (float)tanh(inv_dkey(T));
    if (tid < (int)tc) {
        int myj = tie_idx[tid];
        unsigned rank = 0;
        for (unsigned q = 0; q < tc; ++q) rank += (tie_idx[q] < myj) ? 1u : 0u;
        if (rank < rem) {
            unsigned pos = atomicAdd(&sh_cnt, 1u);
            sel_idx[base_sel + pos] = myj;
            sel_w[base_sel + pos]   = wT;
        }
    }
}

// ---------- kernel 4: weighted mean of selected x rows ----------
// 32 segments x 32 chunks = 1024 blocks; thread = column; 32 rows/block.
__global__ __launch_bounds__(256) void pool_kernel(
    const float* __restrict__ x_inst, const float* __restrict__ x_data,
    const int* __restrict__ sel_idx, const float* __restrict__ sel_w,
    float* __restrict__ out)
{
    __shared__ int   ridx[32];
    __shared__ float rw[32];
    int tid   = threadIdx.x;
    int seg   = blockIdx.x >> 5;
    int chunk = blockIdx.x & 31;
    int side  = seg >> 4;
    int b     = seg & 15;
    int base_sel = seg * Kc + chunk * 32;
    if (tid < 32) { ridx[tid] = sel_idx[base_sel + tid]; rw[tid] = sel_w[base_sel + tid]; }
    __syncthreads();
    const float* x = side ? x_data : x_inst;
    float acc = 0.0f;
#pragma unroll
    for (int r = 0; r < 32; ++r) {
        acc += x[((size_t)(b * NPGc + ridx[r])) * Cc + tid] * rw[r];
    }
    unsafeAtomicAdd(&out[b * 512 + side * 256 + tid], acc * (1.0f / (float)Kc));
}

extern "C" void kernel_launch(void* const* d_in, const int* in_sizes, int n_in,
                              void* d_out, int out_size, void* d_ws, size_t ws_size,
                              hipStream_t stream) {
    const float* x_inst     = (const float*)d_in[0];
    const float* x_data     = (const float*)d_in[1];
    const float* w_kqv_inst = (const float*)d_in[2];
    const float* b_kqv_inst = (const float*)d_in[3];
    const float* w_kqv_data = (const float*)d_in[4];
    const float* b_kqv_data = (const float*)d_in[5];
    const float* w_out_inst = (const float*)d_in[6];
    const float* b_out_inst = (const float*)d_in[7];
    const float* w_out_data = (const float*)d_in[8];
    const float* b_out_data = (const float*)d_in[9];
    const float* krel_w     = (const float*)d_in[10];
    const float* krel_b     = (const float*)d_in[11];
    const float* vrel_w     = (const float*)d_in[12];
    const float* vrel_b     = (const float*)d_in[13];
    const float* p_rel      = (const float*)d_in[14];
    const int*   ei_i2d     = (const int*)d_in[15];
    const int*   ei_d2i     = (const int*)d_in[16];
    const int*   ei_i2i     = (const int*)d_in[17];
    float* out = (float*)d_out;

    // workspace layout (bytes)
    char* ws = (char*)d_ws;
    double* k_i    = (double*)ws;                        // N
    double* v_i    = k_i + Nc;                           // N
    double* k_d    = v_i + Nc;                           // N
    double* v_d    = k_d + Nc;                           // N
    double* q_glob = v_d + Nc;                           // 2N
    size_t off_den = (size_t)6 * Nc * sizeof(double);    // 3,145,728
    double* den    = (double*)(ws + off_den);            // 2N
    double* num    = den + 2 * Nc;                       // 2N
    size_t off_sel = off_den + (size_t)4 * Nc * sizeof(double);
    int*   sel_idx = (int*)(ws + off_sel);               // 32*K
    float* sel_w   = (float*)(ws + off_sel + 32 * Kc * sizeof(int));

    // zero the atomic accumulators and the output
    hipMemsetAsync(ws + off_den, 0, (size_t)4 * Nc * sizeof(double), stream);
    hipMemsetAsync(d_out, 0, (size_t)out_size * sizeof(float), stream);

    // 1) kqv for both sides: 2N rows, 1 wave/row, 4 waves/block
    kqv_kernel<<<(2 * Nc) / 4, 256, 0, stream>>>(
        x_inst, x_data, w_kqv_inst, b_kqv_inst, w_kqv_data, b_kqv_data,
        k_i, v_i, k_d, v_d, q_glob);

    // 2) edge pass: 3E threads
    edge_kernel<<<(3 * Ec) / 256, 256, 0, stream>>>(
        ei_i2d, ei_d2i, ei_i2i, krel_w, krel_b, vrel_w, vrel_b, p_rel,
        k_i, v_i, k_d, v_d, q_glob, den, num);

    // 3) score + top-K select: one block per (side,batch)
    select_kernel<<<32, 256, 0, stream>>>(
        den, num, w_out_inst, b_out_inst, w_out_data, b_out_data,
        sel_idx, sel_w);

    // 4) pooled weighted mean
    pool_kernel<<<1024, 256, 0, stream>>>(x_inst, x_data, sel_idx, sel_w, out);
}

// Round 3
// 360.926 us; speedup vs baseline: 1.6962x; 1.4565x over previous
//
#include <hip/hip_runtime.h>
#include <math.h>

// Problem constants
constexpr int BB   = 16;
constexpr int NPGc = 4096;
constexpr int Cc   = 256;
constexpr int Nc   = BB * NPGc;      // 65536
constexpr int Ec   = Nc * 16;        // 1048576 = 1<<20
constexpr int Kc   = 1024;           // ceil(0.25*4096)
constexpr int NBUK = 1024;           // dst buckets
constexpr int BUKW = 128;            // dst per bucket (2N / NBUK)
constexpr int CHUNK = 16384;         // edges per count/fill block
constexpr int NCHUNK = (3 * Ec) / CHUNK;   // 192

// ---------- monotonic double <-> u64 key ----------
__device__ __forceinline__ unsigned long long dkey(double f) {
    long long b = __double_as_longlong(f);
    unsigned long long u = (unsigned long long)b;
    return (b < 0) ? ~u : (u | 0x8000000000000000ULL);
}
__device__ __forceinline__ double inv_dkey(unsigned long long u) {
    unsigned long long b = (u & 0x8000000000000000ULL) ? (u ^ 0x8000000000000000ULL) : ~u;
    return __longlong_as_double((long long)b);
}

// ---------- kernel 1: kqv = x @ w + b ----------
// 16 lanes per row (4 rows/wave, 16 rows/block): lane covers 16 columns via
// 4 float4 loads (coalesced 256B per group per iter); fp64 accumulate;
// 4-step xor-shuffle reduce within the 16-lane group.
__global__ __launch_bounds__(256) void kqv_kernel(
    const float* __restrict__ x_inst, const float* __restrict__ x_data,
    const float* __restrict__ w_inst, const float* __restrict__ b_inst,
    const float* __restrict__ w_data, const float* __restrict__ b_data,
    double* __restrict__ k_i, double* __restrict__ v_i,
    double* __restrict__ k_d, double* __restrict__ v_d,
    double* __restrict__ q_glob)
{
    int tid  = threadIdx.x;
    int wave = tid >> 6, lane = tid & 63;
    int grp  = lane >> 4, l = lane & 15;
    int row  = blockIdx.x * 16 + wave * 4 + grp;   // 0..2N-1
    int side = (row >= Nc) ? 1 : 0;
    int node = row - side * Nc;
    const float* x  = side ? x_data : x_inst;
    const float* w  = side ? w_data : w_inst;
    const float* bb = side ? b_data : b_inst;

    const float4* rp = (const float4*)(x + (size_t)node * Cc);
    double kk = 0.0, qq = 0.0, vv = 0.0;
#pragma unroll
    for (int it = 0; it < 4; ++it) {
        float4 xv = rp[it * 16 + l];
        float xs[4] = {xv.x, xv.y, xv.z, xv.w};
        int cbase = it * 64 + l * 4;
#pragma unroll
        for (int u = 0; u < 4; ++u) {
            double xd = (double)xs[u];
            const float* wp = w + (cbase + u) * 3;
            kk += xd * (double)wp[0];
            qq += xd * (double)wp[1];
            vv += xd * (double)wp[2];
        }
    }
#pragma unroll
    for (int off = 8; off; off >>= 1) {
        kk += __shfl_xor(kk, off, 64);
        qq += __shfl_xor(qq, off, 64);
        vv += __shfl_xor(vv, off, 64);
    }
    if (l == 0) {
        kk += (double)bb[0]; qq += (double)bb[1]; vv += (double)bb[2];
        if (side) { k_d[node] = kk; v_d[node] = vv; q_glob[Nc + node] = qq; }
        else      { k_i[node] = kk; v_i[node] = vv; q_glob[node]      = qq; }
    }
}

// ---------- helpers for edge id mapping ----------
// global edge id e in [0, 3E): t = e>>20, i = e & (E-1). CHUNK divides E, so t
// is uniform per block.
__device__ __forceinline__ int edge_dg(const int* ei0, const int* ei1,
                                       const int* ei2, unsigned e) {
    int t = (int)(e >> 20);
    int i = (int)(e & (unsigned)(Ec - 1));
    const int* ei = (t == 0) ? ei0 : (t == 1) ? ei1 : ei2;
    int d = ei[Ec + i];
    return d + ((t == 0) ? Nc : 0);
}

// ---------- kernel 2a: per-bucket edge counts ----------
__global__ __launch_bounds__(256) void count_kernel(
    const int* __restrict__ ei0, const int* __restrict__ ei1,
    const int* __restrict__ ei2, unsigned* __restrict__ bucket_cnt)
{
    __shared__ unsigned hist[NBUK];
    int tid = threadIdx.x;
    for (int j = tid; j < NBUK; j += 256) hist[j] = 0;
    __syncthreads();
    unsigned base = blockIdx.x * (unsigned)CHUNK;
#pragma unroll 4
    for (int j = 0; j < CHUNK / 256; ++j) {
        unsigned e = base + j * 256 + tid;
        int dg = edge_dg(ei0, ei1, ei2, e);
        atomicAdd(&hist[dg >> 7], 1u);
    }
    __syncthreads();
    for (int j = tid; j < NBUK; j += 256)
        if (hist[j]) atomicAdd(&bucket_cnt[j], hist[j]);
}

// ---------- kernel 2b: exclusive scan of bucket counts ----------
__global__ __launch_bounds__(1024) void scan_kernel(
    const unsigned* __restrict__ bucket_cnt,
    unsigned* __restrict__ bucket_base, unsigned* __restrict__ bucket_fill)
{
    __shared__ unsigned s[NBUK];
    int t = threadIdx.x;
    unsigned mine = bucket_cnt[t];
    s[t] = mine;
    __syncthreads();
    for (int off = 1; off < NBUK; off <<= 1) {
        unsigned v = (t >= off) ? s[t - off] : 0u;
        __syncthreads();
        s[t] += v;
        __syncthreads();
    }
    unsigned ex = s[t] - mine;
    bucket_base[t] = ex;
    bucket_fill[t] = ex;
    if (t == NBUK - 1) bucket_base[NBUK] = s[t];
}

// ---------- kernel 2c: scatter packed edge records into bucket order ----------
// record = i | (t<<20) | ((dg&127)<<22)
__global__ __launch_bounds__(256) void fill_kernel(
    const int* __restrict__ ei0, const int* __restrict__ ei1,
    const int* __restrict__ ei2, unsigned* __restrict__ bucket_fill,
    unsigned* __restrict__ sorted)
{
    __shared__ unsigned hist[NBUK];
    __shared__ unsigned res[NBUK];
    int tid = threadIdx.x;
    for (int j = tid; j < NBUK; j += 256) hist[j] = 0;
    __syncthreads();
    unsigned base = blockIdx.x * (unsigned)CHUNK;
#pragma unroll 4
    for (int j = 0; j < CHUNK / 256; ++j) {
        unsigned e = base + j * 256 + tid;
        int dg = edge_dg(ei0, ei1, ei2, e);
        atomicAdd(&hist[dg >> 7], 1u);
    }
    __syncthreads();
    for (int j = tid; j < NBUK; j += 256) {
        unsigned h = hist[j];
        res[j] = h ? atomicAdd(&bucket_fill[j], h) : 0u;
        hist[j] = 0;           // reuse as local fill counter
    }
    __syncthreads();
#pragma unroll 4
    for (int j = 0; j < CHUNK / 256; ++j) {
        unsigned e = base + j * 256 + tid;
        int t = (int)(e >> 20);
        int i = (int)(e & (unsigned)(Ec - 1));
        const int* ei = (t == 0) ? ei0 : (t == 1) ? ei1 : ei2;
        int dg = ei[Ec + i] + ((t == 0) ? Nc : 0);
        int bkt = dg >> 7;
        unsigned local = atomicAdd(&hist[bkt], 1u);
        sorted[res[bkt] + local] =
            (unsigned)i | ((unsigned)t << 20) | ((unsigned)(dg & 127) << 22);
    }
}

// ---------- kernel 2d: per-bucket LDS accumulation (no global atomics) ----------
__global__ __launch_bounds__(256) void bucket_accum_kernel(
    const unsigned* __restrict__ bucket_base, const unsigned* __restrict__ sorted,
    const int* __restrict__ ei0, const int* __restrict__ ei1,
    const int* __restrict__ ei2,
    const float* __restrict__ krel_w, const float* __restrict__ krel_b,
    const float* __restrict__ vrel_w, const float* __restrict__ vrel_b,
    const float* __restrict__ p_rel,
    const double* __restrict__ k_i, const double* __restrict__ v_i,
    const double* __restrict__ k_d, const double* __restrict__ v_d,
    const double* __restrict__ q_glob,
    double* __restrict__ den, double* __restrict__ num)
{
    __shared__ double den_l[BUKW];
    __shared__ double num_l[BUKW];
    __shared__ double q_l[BUKW];
    int tid = threadIdx.x;
    int b   = blockIdx.x;
    if (tid < BUKW) {
        den_l[tid] = 0.0;
        num_l[tid] = 0.0;
        q_l[tid]   = q_glob[b * BUKW + tid];
    }
    // broadcast the 15 tiny params into registers
    double kw0 = krel_w[0], kw1 = krel_w[1], kw2 = krel_w[2];
    double kb0 = krel_b[0], kb1 = krel_b[1], kb2 = krel_b[2];
    double vw0 = vrel_w[0], vw1 = vrel_w[1], vw2 = vrel_w[2];
    double vb0 = vrel_b[0], vb1 = vrel_b[1], vb2 = vrel_b[2];
    double pr0 = p_rel[0],  pr1 = p_rel[1],  pr2 = p_rel[2];
    unsigned beg = bucket_base[b], end = bucket_base[b + 1];
    __syncthreads();

    for (unsigned e = beg + tid; e < end; e += 256) {
        unsigned r = sorted[e];
        int i    = (int)(r & 0xFFFFFu);
        int t    = (int)((r >> 20) & 3u);
        int low7 = (int)((r >> 22) & 127u);
        const int*    ei = (t == 0) ? ei0 : (t == 1) ? ei1 : ei2;
        const double* ks = (t == 1) ? k_d : k_i;
        const double* vs = (t == 1) ? v_d : v_i;
        int s = ei[i];
        double kwt = (t == 0) ? kw0 : (t == 1) ? kw1 : kw2;
        double kbt = (t == 0) ? kb0 : (t == 1) ? kb1 : kb2;
        double vwt = (t == 0) ? vw0 : (t == 1) ? vw1 : vw2;
        double vbt = (t == 0) ? vb0 : (t == 1) ? vb1 : vb2;
        double prt = (t == 0) ? pr0 : (t == 1) ? pr1 : pr2;
        double ke = ks[s] * kwt + kbt;
        double ve = vs[s] * vwt + vbt;
        double logit = q_l[low7] * ke * prt;
        double ex = exp(logit);
        atomicAdd(&den_l[low7], ex);
        atomicAdd(&num_l[low7], ex * ve);
    }
    __syncthreads();
    if (tid < BUKW) {
        den[b * BUKW + tid] = den_l[tid];   // plain stores — no global atomics
        num[b * BUKW + tid] = num_l[tid];
    }
}

// ---------- kernel 3: gelu score + radix top-K select per (side,batch) ----------
__global__ __launch_bounds__(256) void select_kernel(
    const double* __restrict__ den, const double* __restrict__ num,
    const float* __restrict__ w_out_inst, const float* __restrict__ b_out_inst,
    const float* __restrict__ w_out_data, const float* __restrict__ b_out_data,
    int* __restrict__ sel_idx, float* __restrict__ sel_w)
{
    __shared__ unsigned long long keys[NPGc];   // 32 KB
    __shared__ unsigned hist[256];
    __shared__ unsigned suf[256];
    __shared__ unsigned sh_chosen, sh_rem, sh_rem2, sh_cnt, sh_tiecnt;
    __shared__ int tie_idx[256];

    int tid  = threadIdx.x;
    int seg  = blockIdx.x;          // 0..31
    int side = seg >> 4;
    int b    = seg & 15;
    double wo = side ? (double)w_out_data[0] : (double)w_out_inst[0];
    double bo = side ? (double)b_out_data[0] : (double)b_out_inst[0];
    int base_node = side * Nc + b * NPGc;

    for (int ii = 0; ii < 16; ++ii) {
        int j = ii * 256 + tid;
        double dn = den[base_node + j];
        double a  = (dn > 0.0) ? num[base_node + j] / dn : 0.0;
        double z  = a * wo + bo;
        double s  = 0.5 * z * (1.0 + erf(z * 0.7071067811865476));  // exact gelu
        keys[j] = dkey(s);
    }
    if (tid == 0) { sh_rem = Kc; sh_cnt = 0; sh_tiecnt = 0; }
    __syncthreads();

    unsigned long long prefix = 0ULL;
    for (int p = 7; p >= 0; --p) {
        hist[tid] = 0;
        __syncthreads();
        for (int ii = 0; ii < 16; ++ii) {
            unsigned long long k64 = keys[ii * 256 + tid];
            bool cand = (p == 7) || ((k64 >> ((p + 1) * 8)) == prefix);
            if (cand) atomicAdd(&hist[(unsigned)(k64 >> (p * 8)) & 255u], 1u);
        }
        __syncthreads();
        suf[tid] = hist[tid];
        __syncthreads();
        for (int ofs = 1; ofs < 256; ofs <<= 1) {
            unsigned add = (tid + ofs < 256) ? suf[tid + ofs] : 0u;
            __syncthreads();
            suf[tid] += add;
            __syncthreads();
        }
        unsigned below = (tid == 255) ? 0u : suf[tid + 1];
        if (suf[tid] >= sh_rem && below < sh_rem) {
            sh_chosen = (unsigned)tid;
            sh_rem2   = sh_rem - below;
        }
        __syncthreads();
        if (tid == 0) sh_rem = sh_rem2;
        __syncthreads();
        prefix = (prefix << 8) | (unsigned long long)sh_chosen;
    }
    unsigned long long T = prefix;     // exact key of the K-th largest
    unsigned rem = sh_rem;             // #ties at T to take (lowest index first)

    int base_sel = seg * Kc;
    for (int ii = 0; ii < 16; ++ii) {
        int j = ii * 256 + tid;
        unsigned long long k64 = keys[j];
        if (k64 > T) {
            unsigned pos = atomicAdd(&sh_cnt, 1u);
            sel_idx[base_sel + pos] = j;
            sel_w[base_sel + pos]   = (float)tanh(inv_dkey(k64));
        } else if (k64 == T) {
            unsigned tp = atomicAdd(&sh_tiecnt, 1u);
            if (tp < 256u) tie_idx[tp] = j;
        }
    }
    __syncthreads();
    unsigned tc = min(sh_tiecnt, 256u);
    float wT = (float)tanh(inv_dkey(T));
    if (tid < (int)tc) {
        int myj = tie_idx[tid];
        unsigned rank = 0;
        for (unsigned q = 0; q < tc; ++q) rank += (tie_idx[q] < myj) ? 1u : 0u;
        if (rank < rem) {
            unsigned pos = atomicAdd(&sh_cnt, 1u);
            sel_idx[base_sel + pos] = myj;
            sel_w[base_sel + pos]   = wT;
        }
    }
}

// ---------- kernel 4: weighted mean of selected x rows ----------
__global__ __launch_bounds__(256) void pool_kernel(
    const float* __restrict__ x_inst, const float* __restrict__ x_data,
    const int* __restrict__ sel_idx, const float* __restrict__ sel_w,
    float* __restrict__ out)
{
    __shared__ int   ridx[32];
    __shared__ float rw[32];
    int tid   = threadIdx.x;
    int seg   = blockIdx.x >> 5;
    int chunk = blockIdx.x & 31;
    int side  = seg >> 4;
    int b     = seg & 15;
    int base_sel = seg * Kc + chunk * 32;
    if (tid < 32) { ridx[tid] = sel_idx[base_sel + tid]; rw[tid] = sel_w[base_sel + tid]; }
    __syncthreads();
    const float* x = side ? x_data : x_inst;
    float acc = 0.0f;
#pragma unroll
    for (int r = 0; r < 32; ++r) {
        acc += x[((size_t)(b * NPGc + ridx[r])) * Cc + tid] * rw[r];
    }
    unsafeAtomicAdd(&out[b * 512 + side * 256 + tid], acc * (1.0f / (float)Kc));
}

extern "C" void kernel_launch(void* const* d_in, const int* in_sizes, int n_in,
                              void* d_out, int out_size, void* d_ws, size_t ws_size,
                              hipStream_t stream) {
    const float* x_inst     = (const float*)d_in[0];
    const float* x_data     = (const float*)d_in[1];
    const float* w_kqv_inst = (const float*)d_in[2];
    const float* b_kqv_inst = (const float*)d_in[3];
    const float* w_kqv_data = (const float*)d_in[4];
    const float* b_kqv_data = (const float*)d_in[5];
    const float* w_out_inst = (const float*)d_in[6];
    const float* b_out_inst = (const float*)d_in[7];
    const float* w_out_data = (const float*)d_in[8];
    const float* b_out_data = (const float*)d_in[9];
    const float* krel_w     = (const float*)d_in[10];
    const float* krel_b     = (const float*)d_in[11];
    const float* vrel_w     = (const float*)d_in[12];
    const float* vrel_b     = (const float*)d_in[13];
    const float* p_rel      = (const float*)d_in[14];
    const int*   ei_i2d     = (const int*)d_in[15];
    const int*   ei_d2i     = (const int*)d_in[16];
    const int*   ei_i2i     = (const int*)d_in[17];
    float* out = (float*)d_out;

    // workspace layout
    char* ws = (char*)d_ws;
    double* k_i    = (double*)ws;                        // N
    double* v_i    = k_i + Nc;
    double* k_d    = v_i + Nc;
    double* v_d    = k_d + Nc;
    double* q_glob = v_d + Nc;                           // 2N
    double* den    = q_glob + 2 * Nc;                    // 2N
    double* num    = den + 2 * Nc;                       // 2N
    unsigned* bucket_cnt  = (unsigned*)(num + 2 * Nc);   // NBUK
    unsigned* bucket_base = bucket_cnt + NBUK;           // NBUK+1
    unsigned* bucket_fill = bucket_base + NBUK + 1;      // NBUK
    int*      sel_idx     = (int*)(bucket_fill + NBUK);  // 32*K
    float*    sel_w       = (float*)(sel_idx + 32 * Kc); // 32*K
    unsigned* sorted      = (unsigned*)(sel_w + 32 * Kc);// 3E  (12.6 MB)

    hipMemsetAsync(bucket_cnt, 0, NBUK * sizeof(unsigned), stream);
    hipMemsetAsync(d_out, 0, (size_t)out_size * sizeof(float), stream);

    // 1) kqv for both sides: 16 rows per block
    kqv_kernel<<<(2 * Nc) / 16, 256, 0, stream>>>(
        x_inst, x_data, w_kqv_inst, b_kqv_inst, w_kqv_data, b_kqv_data,
        k_i, v_i, k_d, v_d, q_glob);

    // 2) edge path: count -> scan -> fill -> per-bucket LDS accumulate
    count_kernel<<<NCHUNK, 256, 0, stream>>>(ei_i2d, ei_d2i, ei_i2i, bucket_cnt);
    scan_kernel<<<1, NBUK, 0, stream>>>(bucket_cnt, bucket_base, bucket_fill);
    fill_kernel<<<NCHUNK, 256, 0, stream>>>(ei_i2d, ei_d2i, ei_i2i,
                                            bucket_fill, sorted);
    bucket_accum_kernel<<<NBUK, 256, 0, stream>>>(
        bucket_base, sorted, ei_i2d, ei_d2i, ei_i2i,
        krel_w, krel_b, vrel_w, vrel_b, p_rel,
        k_i, v_i, k_d, v_d, q_glob, den, num);

    // 3) score + top-K select
    select_kernel<<<32, 256, 0, stream>>>(
        den, num, w_out_inst, b_out_inst, w_out_data, b_out_data,
        sel_idx, sel_w);

    // 4) pooled weighted mean
    pool_kernel<<<1024, 256, 0, stream>>>(x_inst, x_data, sel_idx, sel_w, out);
}

// Round 5
// 323.048 us; speedup vs baseline: 1.8951x; 1.1173x over previous
//
#include <hip/hip_runtime.h>
#include <math.h>

// Problem constants
constexpr int BB   = 16;
constexpr int NPGc = 4096;
constexpr int Cc   = 256;
constexpr int Nc   = BB * NPGc;      // 65536
constexpr int Ec   = Nc * 16;        // 1048576 = 1<<20
constexpr int Kc   = 1024;           // ceil(0.25*4096)
constexpr int NBUK = 1024;           // dst buckets
constexpr int BUKW = 128;            // dst per bucket (2N / NBUK)
constexpr int CHUNK = 16384;         // edges per count/fill block
constexpr int NCHUNK = (3 * Ec) / CHUNK;   // 192

// ---------- monotonic double <-> u64 key ----------
__device__ __forceinline__ unsigned long long dkey(double f) {
    long long b = __double_as_longlong(f);
    unsigned long long u = (unsigned long long)b;
    return (b < 0) ? ~u : (u | 0x8000000000000000ULL);
}
__device__ __forceinline__ double inv_dkey(unsigned long long u) {
    unsigned long long b = (u & 0x8000000000000000ULL) ? (u ^ 0x8000000000000000ULL) : ~u;
    return __longlong_as_double((long long)b);
}

// ---------- kernel 1: kqv = x @ w + b ----------
// 16 lanes per row-group, 8 rows per group. w hoisted into 48 fp64 regs once
// per group (3 float4 loads/lane), reused across 8 rows.
__global__ __launch_bounds__(256) void kqv_kernel(
    const float* __restrict__ x_inst, const float* __restrict__ x_data,
    const float* __restrict__ w_inst, const float* __restrict__ b_inst,
    const float* __restrict__ w_data, const float* __restrict__ b_data,
    double* __restrict__ k_i, double* __restrict__ v_i,
    double* __restrict__ k_d, double* __restrict__ v_d,
    double* __restrict__ q_glob)
{
    int tid  = threadIdx.x;
    int wave = tid >> 6, lane = tid & 63;
    int grp  = lane >> 4, l = lane & 15;
    int g    = blockIdx.x * 16 + wave * 4 + grp;   // group id, 8 rows each
    int row0 = g * 8;                              // 0..2N-1, side-uniform
    int side = (row0 >= Nc) ? 1 : 0;
    int node0 = row0 - side * Nc;
    const float* x  = side ? x_data : x_inst;
    const float* w  = side ? w_data : w_inst;
    const float* bp = side ? b_data : b_inst;

    double wr[48];
#pragma unroll
    for (int it = 0; it < 4; ++it) {
        const float4* wv = (const float4*)(w + (it * 64 + l * 4) * 3);
        float4 f0 = wv[0], f1 = wv[1], f2 = wv[2];
        float wt[12] = {f0.x, f0.y, f0.z, f0.w, f1.x, f1.y, f1.z, f1.w,
                        f2.x, f2.y, f2.z, f2.w};
#pragma unroll
        for (int e = 0; e < 12; ++e) wr[it * 12 + e] = (double)wt[e];
    }
    double b0 = (double)bp[0], b1 = (double)bp[1], b2 = (double)bp[2];

    const float4* rp = (const float4*)(x + (size_t)node0 * Cc);
#pragma unroll 2
    for (int r = 0; r < 8; ++r) {
        double kk = 0.0, qq = 0.0, vv = 0.0;
#pragma unroll
        for (int it = 0; it < 4; ++it) {
            float4 xv = rp[r * 64 + it * 16 + l];
            float xs[4] = {xv.x, xv.y, xv.z, xv.w};
#pragma unroll
            for (int u = 0; u < 4; ++u) {
                double xd = (double)xs[u];
                kk += xd * wr[it * 12 + u * 3 + 0];
                qq += xd * wr[it * 12 + u * 3 + 1];
                vv += xd * wr[it * 12 + u * 3 + 2];
            }
        }
#pragma unroll
        for (int off = 8; off; off >>= 1) {
            kk += __shfl_xor(kk, off, 64);
            qq += __shfl_xor(qq, off, 64);
            vv += __shfl_xor(vv, off, 64);
        }
        if (l == 0) {
            int node = node0 + r;
            kk += b0; qq += b1; vv += b2;
            if (side) { k_d[node] = kk; v_d[node] = vv; q_glob[Nc + node] = qq; }
            else      { k_i[node] = kk; v_i[node] = vv; q_glob[node]      = qq; }
        }
    }
}

// ---------- kernel 2a: per-bucket edge counts (int4 loads) ----------
__global__ __launch_bounds__(256) void count_kernel(
    const int* __restrict__ ei0, const int* __restrict__ ei1,
    const int* __restrict__ ei2, unsigned* __restrict__ bucket_cnt)
{
    __shared__ unsigned hist[NBUK];
    int tid = threadIdx.x;
    for (int j = tid; j < NBUK; j += 256) hist[j] = 0;
    __syncthreads();
    unsigned base = blockIdx.x * (unsigned)CHUNK;
    int t = (int)(base >> 20);
    unsigned i0 = base & (unsigned)(Ec - 1);
    const int* ei = (t == 0) ? ei0 : (t == 1) ? ei1 : ei2;
    int off = (t == 0) ? Nc : 0;
    const int4* dv = (const int4*)(ei + Ec + i0);
#pragma unroll 4
    for (int j = 0; j < CHUNK / 1024; ++j) {
        int4 d4 = dv[j * 256 + tid];
        atomicAdd(&hist[(unsigned)(d4.x + off) >> 7], 1u);
        atomicAdd(&hist[(unsigned)(d4.y + off) >> 7], 1u);
        atomicAdd(&hist[(unsigned)(d4.z + off) >> 7], 1u);
        atomicAdd(&hist[(unsigned)(d4.w + off) >> 7], 1u);
    }
    __syncthreads();
    for (int j = tid; j < NBUK; j += 256)
        if (hist[j]) atomicAdd(&bucket_cnt[j], hist[j]);
}

// ---------- kernel 2b: exclusive scan of bucket counts ----------
__global__ __launch_bounds__(1024) void scan_kernel(
    const unsigned* __restrict__ bucket_cnt,
    unsigned* __restrict__ bucket_base, unsigned* __restrict__ bucket_fill)
{
    __shared__ unsigned s[NBUK];
    int t = threadIdx.x;
    unsigned mine = bucket_cnt[t];
    s[t] = mine;
    __syncthreads();
    for (int off = 1; off < NBUK; off <<= 1) {
        unsigned v = (t >= off) ? s[t - off] : 0u;
        __syncthreads();
        s[t] += v;
        __syncthreads();
    }
    unsigned ex = s[t] - mine;
    bucket_base[t] = ex;
    bucket_fill[t] = ex;
    if (t == NBUK - 1) bucket_base[NBUK] = s[t];
}

// ---------- kernel 2c: scatter packed records into bucket order ----------
// record = s(16 bits) | t<<16 | (dg&127)<<18  -> accum never touches ei again
__global__ __launch_bounds__(256) void fill_kernel(
    const int* __restrict__ ei0, const int* __restrict__ ei1,
    const int* __restrict__ ei2, unsigned* __restrict__ bucket_fill,
    unsigned* __restrict__ sorted)
{
    __shared__ unsigned hist[NBUK];
    __shared__ unsigned res[NBUK];
    int tid = threadIdx.x;
    for (int j = tid; j < NBUK; j += 256) hist[j] = 0;
    __syncthreads();
    unsigned base = blockIdx.x * (unsigned)CHUNK;
    int t = (int)(base >> 20);
    unsigned i0 = base & (unsigned)(Ec - 1);
    const int* ei = (t == 0) ? ei0 : (t == 1) ? ei1 : ei2;
    int off = (t == 0) ? Nc : 0;
    const int4* dv = (const int4*)(ei + Ec + i0);
    const int4* sv = (const int4*)(ei + i0);
#pragma unroll 4
    for (int j = 0; j < CHUNK / 1024; ++j) {
        int4 d4 = dv[j * 256 + tid];
        atomicAdd(&hist[(unsigned)(d4.x + off) >> 7], 1u);
        atomicAdd(&hist[(unsigned)(d4.y + off) >> 7], 1u);
        atomicAdd(&hist[(unsigned)(d4.z + off) >> 7], 1u);
        atomicAdd(&hist[(unsigned)(d4.w + off) >> 7], 1u);
    }
    __syncthreads();
    for (int j = tid; j < NBUK; j += 256) {
        unsigned h = hist[j];
        res[j] = h ? atomicAdd(&bucket_fill[j], h) : 0u;
        hist[j] = 0;           // reuse as local fill counter
    }
    __syncthreads();
#pragma unroll 4
    for (int j = 0; j < CHUNK / 1024; ++j) {
        int4 d4 = dv[j * 256 + tid];
        int4 s4 = sv[j * 256 + tid];
        int dd[4] = {d4.x, d4.y, d4.z, d4.w};
        int ss[4] = {s4.x, s4.y, s4.z, s4.w};
#pragma unroll
        for (int u = 0; u < 4; ++u) {
            int dg  = dd[u] + off;
            int bkt = dg >> 7;
            unsigned local = atomicAdd(&hist[bkt], 1u);
            sorted[res[bkt] + local] =
                (unsigned)ss[u] | ((unsigned)t << 16) | ((unsigned)(dg & 127) << 18);
        }
    }
}

// ---------- kernel 2d: per-bucket LDS accumulation ----------
__global__ __launch_bounds__(256) void bucket_accum_kernel(
    const unsigned* __restrict__ bucket_base, const unsigned* __restrict__ sorted,
    const float* __restrict__ krel_w, const float* __restrict__ krel_b,
    const float* __restrict__ vrel_w, const float* __restrict__ vrel_b,
    const float* __restrict__ p_rel,
    const double* __restrict__ k_i, const double* __restrict__ v_i,
    const double* __restrict__ k_d, const double* __restrict__ v_d,
    const double* __restrict__ q_glob,
    double* __restrict__ den, double* __restrict__ num)
{
    __shared__ double den_l[BUKW];
    __shared__ double num_l[BUKW];
    __shared__ double q_l[BUKW];
    int tid = threadIdx.x;
    int b   = blockIdx.x;
    if (tid < BUKW) {
        den_l[tid] = 0.0;
        num_l[tid] = 0.0;
        q_l[tid]   = q_glob[b * BUKW + tid];
    }
    double kw0 = krel_w[0], kw1 = krel_w[1], kw2 = krel_w[2];
    double kb0 = krel_b[0], kb1 = krel_b[1], kb2 = krel_b[2];
    double vw0 = vrel_w[0], vw1 = vrel_w[1], vw2 = vrel_w[2];
    double vb0 = vrel_b[0], vb1 = vrel_b[1], vb2 = vrel_b[2];
    double pr0 = p_rel[0],  pr1 = p_rel[1],  pr2 = p_rel[2];
    unsigned beg = bucket_base[b], end = bucket_base[b + 1];
    __syncthreads();

    for (unsigned e = beg + tid; e < end; e += 256) {
        unsigned r = sorted[e];
        int s    = (int)(r & 0xFFFFu);
        int t    = (int)((r >> 16) & 3u);
        int low7 = (int)((r >> 18) & 127u);
        const double* ks = (t == 1) ? k_d : k_i;
        const double* vs = (t == 1) ? v_d : v_i;
        double kwt = (t == 0) ? kw0 : (t == 1) ? kw1 : kw2;
        double kbt = (t == 0) ? kb0 : (t == 1) ? kb1 : kb2;
        double vwt = (t == 0) ? vw0 : (t == 1) ? vw1 : vw2;
        double vbt = (t == 0) ? vb0 : (t == 1) ? vb1 : vb2;
        double prt = (t == 0) ? pr0 : (t == 1) ? pr1 : pr2;
        double ke = ks[s] * kwt + kbt;
        double ve = vs[s] * vwt + vbt;
        double ex = exp(q_l[low7] * ke * prt);
        __hip_atomic_fetch_add(&den_l[low7], ex, __ATOMIC_RELAXED,
                               __HIP_MEMORY_SCOPE_WORKGROUP);
        __hip_atomic_fetch_add(&num_l[low7], ex * ve, __ATOMIC_RELAXED,
                               __HIP_MEMORY_SCOPE_WORKGROUP);
    }
    __syncthreads();
    if (tid < BUKW) {
        den[b * BUKW + tid] = den_l[tid];   // plain stores
        num[b * BUKW + tid] = num_l[tid];
    }
}

// ---------- kernel 3: score + 2-level radix top-K (1024 threads/block) ----------
__global__ __launch_bounds__(1024) void select_kernel(
    const double* __restrict__ den, const double* __restrict__ num,
    const float* __restrict__ w_out_inst, const float* __restrict__ b_out_inst,
    const float* __restrict__ w_out_data, const float* __restrict__ b_out_data,
    int* __restrict__ sel_idx, float* __restrict__ sel_w)
{
    __shared__ unsigned long long keys[NPGc];   // 32 KB
    __shared__ unsigned hist[2048];             // 8 KB
    __shared__ unsigned wsum[16];
    __shared__ unsigned short cand[NPGc];       // 8 KB
    __shared__ unsigned sh_bin1, sh_rem1, sh_bin2, sh_rem2, sh_cnt, sh_nc;

    int tid  = threadIdx.x;
    int seg  = blockIdx.x;          // 0..31
    int side = seg >> 4;
    int b    = seg & 15;
    double wo = side ? (double)w_out_data[0] : (double)w_out_inst[0];
    double bo = side ? (double)b_out_data[0] : (double)b_out_inst[0];
    int base_node = side * Nc + b * NPGc;
    int base_sel  = seg * Kc;

    // phase 0: scores -> keys (4 per thread, coalesced)
    unsigned long long myk[4]; int myj[4];
#pragma unroll
    for (int p = 0; p < 4; ++p) {
        int j = p * 1024 + tid;
        double dn = den[base_node + j];
        double a  = (dn > 0.0) ? num[base_node + j] / dn : 0.0;
        double z  = a * wo + bo;
        double s  = 0.5 * z * (1.0 + erf(z * 0.7071067811865476));
        unsigned long long k64 = dkey(s);
        keys[j] = k64; myk[p] = k64; myj[p] = j;
    }
    if (tid == 0) { sh_cnt = 0; sh_nc = 0; }
    hist[tid] = 0; hist[tid + 1024] = 0;
    __syncthreads();

    // phase 1: hist over bits [63:53]
#pragma unroll
    for (int p = 0; p < 4; ++p) atomicAdd(&hist[(unsigned)(myk[p] >> 53)], 1u);
    __syncthreads();
    {   // suffix scan (descending bins): thread owns bins {2047-2t, 2046-2t}
        unsigned g0 = hist[2047 - 2 * tid];
        unsigned g1 = hist[2046 - 2 * tid];
        unsigned x = g0 + g1;
        int lane = tid & 63;
#pragma unroll
        for (int off = 1; off < 64; off <<= 1) {
            unsigned y = __shfl_up(x, off, 64);
            if (lane >= off) x += y;
        }
        if (lane == 63) wsum[tid >> 6] = x;
        __syncthreads();
        if (tid < 16) {
            unsigned v = wsum[tid];
#pragma unroll
            for (int off = 1; off < 16; off <<= 1) {
                unsigned y = __shfl_up(v, off, 64);
                if (tid >= off) v += y;
            }
            wsum[tid] = v;
        }
        __syncthreads();
        unsigned basew = (tid >= 64) ? wsum[(tid >> 6) - 1] : 0u;
        unsigned incl  = basew + x;        // suffix-incl at bin 2046-2t
        unsigned incl0 = incl - g1;        // suffix-incl at bin 2047-2t
        unsigned K = Kc;
        if (incl0 >= K && incl0 - g0 < K) { sh_bin1 = 2047 - 2 * tid; sh_rem1 = K - (incl0 - g0); }
        if (incl  >= K && incl  - g1 < K) { sh_bin1 = 2046 - 2 * tid; sh_rem1 = K - (incl  - g1); }
    }
    __syncthreads();
    unsigned bin1 = sh_bin1, rem1 = sh_rem1;
    hist[tid] = 0; hist[tid + 1024] = 0;
    __syncthreads();

    // phase 2: hist over bits [52:42] among bin1 keys
#pragma unroll
    for (int p = 0; p < 4; ++p)
        if ((unsigned)(myk[p] >> 53) == bin1)
            atomicAdd(&hist[(unsigned)(myk[p] >> 42) & 2047u], 1u);
    __syncthreads();
    {
        unsigned g0 = hist[2047 - 2 * tid];
        unsigned g1 = hist[2046 - 2 * tid];
        unsigned x = g0 + g1;
        int lane = tid & 63;
#pragma unroll
        for (int off = 1; off < 64; off <<= 1) {
            unsigned y = __shfl_up(x, off, 64);
            if (lane >= off) x += y;
        }
        if (lane == 63) wsum[tid >> 6] = x;
        __syncthreads();
        if (tid < 16) {
            unsigned v = wsum[tid];
#pragma unroll
            for (int off = 1; off < 16; off <<= 1) {
                unsigned y = __shfl_up(v, off, 64);
                if (tid >= off) v += y;
            }
            wsum[tid] = v;
        }
        __syncthreads();
        unsigned basew = (tid >= 64) ? wsum[(tid >> 6) - 1] : 0u;
        unsigned incl  = basew + x;
        unsigned incl0 = incl - g1;
        unsigned K = rem1;
        if (incl0 >= K && incl0 - g0 < K) { sh_bin2 = 2047 - 2 * tid; sh_rem2 = K - (incl0 - g0); }
        if (incl  >= K && incl  - g1 < K) { sh_bin2 = 2046 - 2 * tid; sh_rem2 = K - (incl  - g1); }
    }
    __syncthreads();
    unsigned long long pref22 = ((unsigned long long)bin1 << 11) | (unsigned long long)sh_bin2;
    unsigned rem2 = sh_rem2;

    // phase 3: classify
#pragma unroll
    for (int p = 0; p < 4; ++p) {
        unsigned long long top22 = myk[p] >> 42;
        if (top22 > pref22) {
            unsigned pos = atomicAdd(&sh_cnt, 1u);
            sel_idx[base_sel + pos] = myj[p];
            sel_w[base_sel + pos]   = (float)tanh(inv_dkey(myk[p]));
        } else if (top22 == pref22) {
            unsigned cp = atomicAdd(&sh_nc, 1u);
            cand[cp] = (unsigned short)myj[p];
        }
    }
    __syncthreads();

    // phase 4: exact rank among candidates (full key desc, index asc)
    unsigned nc = sh_nc;
    for (unsigned c = tid; c < nc; c += 1024) {
        int j = cand[c];
        unsigned long long k64 = keys[j];
        unsigned rank = 0;
        for (unsigned q = 0; q < nc; ++q) {
            int jq = cand[q];
            unsigned long long kq = keys[jq];
            rank += (kq > k64 || (kq == k64 && jq < j)) ? 1u : 0u;
        }
        if (rank < rem2) {
            unsigned pos = atomicAdd(&sh_cnt, 1u);
            sel_idx[base_sel + pos] = j;
            sel_w[base_sel + pos]   = (float)tanh(inv_dkey(k64));
        }
    }
}

// ---------- kernel 4: weighted mean of selected rows ----------
// 32 segs x 8 chunks of 128 rows; 1024 threads = 16 waves; each wave does
// 8 rows (16*8 = 128 — round-4 crash was w*16+r indexing past ridx[128]).
__global__ __launch_bounds__(1024) void pool_kernel(
    const float* __restrict__ x_inst, const float* __restrict__ x_data,
    const int* __restrict__ sel_idx, const float* __restrict__ sel_w,
    float* __restrict__ out)
{
    __shared__ int   ridx[128];
    __shared__ float rw[128];
    __shared__ float accs[256];
    int tid   = threadIdx.x;
    int blk   = blockIdx.x;
    int seg   = blk >> 3;
    int chunk = blk & 7;
    int side  = seg >> 4;
    int b     = seg & 15;
    if (tid < 128) {
        ridx[tid] = sel_idx[seg * Kc + chunk * 128 + tid];
        rw[tid]   = sel_w[seg * Kc + chunk * 128 + tid];
    }
    if (tid < 256) accs[tid] = 0.0f;
    __syncthreads();
    const float* x = side ? x_data : x_inst;
    int w = tid >> 6, l = tid & 63;
    float ax = 0.f, ay = 0.f, az = 0.f, aw = 0.f;
#pragma unroll
    for (int r = 0; r < 8; ++r) {
        int   row = ridx[w * 8 + r];
        float wt  = rw[w * 8 + r];
        float4 xv = ((const float4*)(x + ((size_t)(b * NPGc + row)) * Cc))[l];
        ax += xv.x * wt; ay += xv.y * wt; az += xv.z * wt; aw += xv.w * wt;
    }
    atomicAdd(&accs[l * 4 + 0], ax);
    atomicAdd(&accs[l * 4 + 1], ay);
    atomicAdd(&accs[l * 4 + 2], az);
    atomicAdd(&accs[l * 4 + 3], aw);
    __syncthreads();
    if (tid < 256)
        unsafeAtomicAdd(&out[b * 512 + side * 256 + tid], accs[tid] * (1.0f / (float)Kc));
}

extern "C" void kernel_launch(void* const* d_in, const int* in_sizes, int n_in,
                              void* d_out, int out_size, void* d_ws, size_t ws_size,
                              hipStream_t stream) {
    const float* x_inst     = (const float*)d_in[0];
    const float* x_data     = (const float*)d_in[1];
    const float* w_kqv_inst = (const float*)d_in[2];
    const float* b_kqv_inst = (const float*)d_in[3];
    const float* w_kqv_data = (const float*)d_in[4];
    const float* b_kqv_data = (const float*)d_in[5];
    const float* w_out_inst = (const float*)d_in[6];
    const float* b_out_inst = (const float*)d_in[7];
    const float* w_out_data = (const float*)d_in[8];
    const float* b_out_data = (const float*)d_in[9];
    const float* krel_w     = (const float*)d_in[10];
    const float* krel_b     = (const float*)d_in[11];
    const float* vrel_w     = (const float*)d_in[12];
    const float* vrel_b     = (const float*)d_in[13];
    const float* p_rel      = (const float*)d_in[14];
    const int*   ei_i2d     = (const int*)d_in[15];
    const int*   ei_d2i     = (const int*)d_in[16];
    const int*   ei_i2i     = (const int*)d_in[17];
    float* out = (float*)d_out;

    // workspace layout
    char* ws = (char*)d_ws;
    double* k_i    = (double*)ws;                        // N
    double* v_i    = k_i + Nc;
    double* k_d    = v_i + Nc;
    double* v_d    = k_d + Nc;
    double* q_glob = v_d + Nc;                           // 2N
    double* den    = q_glob + 2 * Nc;                    // 2N
    double* num    = den + 2 * Nc;                       // 2N
    unsigned* bucket_cnt  = (unsigned*)(num + 2 * Nc);   // NBUK
    unsigned* bucket_base = bucket_cnt + NBUK;           // NBUK+1
    unsigned* bucket_fill = bucket_base + NBUK + 1;      // NBUK
    int*      sel_idx     = (int*)(bucket_fill + NBUK);  // 32*K
    float*    sel_w       = (float*)(sel_idx + 32 * Kc); // 32*K
    unsigned* sorted      = (unsigned*)(sel_w + 32 * Kc);// 3E (12.6 MB)

    hipMemsetAsync(bucket_cnt, 0, NBUK * sizeof(unsigned), stream);
    hipMemsetAsync(d_out, 0, (size_t)out_size * sizeof(float), stream);

    // edge path (independent of x): count -> scan -> fill
    count_kernel<<<NCHUNK, 256, 0, stream>>>(ei_i2d, ei_d2i, ei_i2i, bucket_cnt);
    scan_kernel<<<1, NBUK, 0, stream>>>(bucket_cnt, bucket_base, bucket_fill);
    fill_kernel<<<NCHUNK, 256, 0, stream>>>(ei_i2d, ei_d2i, ei_i2i,
                                            bucket_fill, sorted);

    // kqv for both sides: 128 rows per block
    kqv_kernel<<<(2 * Nc) / 128, 256, 0, stream>>>(
        x_inst, x_data, w_kqv_inst, b_kqv_inst, w_kqv_data, b_kqv_data,
        k_i, v_i, k_d, v_d, q_glob);

    // per-bucket LDS accumulate
    bucket_accum_kernel<<<NBUK, 256, 0, stream>>>(
        bucket_base, sorted,
        krel_w, krel_b, vrel_w, vrel_b, p_rel,
        k_i, v_i, k_d, v_d, q_glob, den, num);

    // score + top-K select
    select_kernel<<<32, 1024, 0, stream>>>(
        den, num, w_out_inst, b_out_inst, w_out_data, b_out_data,
        sel_idx, sel_w);

    // pooled weighted mean
    pool_kernel<<<256, 1024, 0, stream>>>(x_inst, x_data, sel_idx, sel_w, out);
}

// Round 6
// 319.893 us; speedup vs baseline: 1.9138x; 1.0099x over previous
//
#include <hip/hip_runtime.h>
#include <math.h>

// Problem constants
constexpr int BB   = 16;
constexpr int NPGc = 4096;
constexpr int Cc   = 256;
constexpr int Nc   = BB * NPGc;      // 65536
constexpr int Ec   = Nc * 16;        // 1048576 = 1<<20
constexpr int Kc   = 1024;           // ceil(0.25*4096)
constexpr int NBUK = 1024;           // dst buckets
constexpr int BUKW = 128;            // dst per bucket (2N / NBUK)
constexpr int CHUNK = 16384;         // edges per count/fill block
constexpr int NCHUNK = (3 * Ec) / CHUNK;   // 192

// ---------- monotonic float <-> u32 key ----------
__device__ __forceinline__ unsigned fkey(float f) {
    int b = __float_as_int(f);
    unsigned u = (unsigned)b;
    return (b < 0) ? ~u : (u | 0x80000000u);
}
__device__ __forceinline__ float inv_fkey(unsigned u) {
    unsigned b = (u & 0x80000000u) ? (u ^ 0x80000000u) : ~u;
    return __int_as_float((int)b);
}

// ---------- kernel 1: kqv = x @ w + b (fp32) ----------
// 16 lanes per row-group, 2 rows/group -> 4096 blocks, 8 independent float4
// loads in flight per thread. w (3 KB) is L1-resident; re-read per group is
// 3 float4 loads/lane — cheap. k,v packed as float2 for the edge gather.
__global__ __launch_bounds__(256) void kqv_kernel(
    const float* __restrict__ x_inst, const float* __restrict__ x_data,
    const float* __restrict__ w_inst, const float* __restrict__ b_inst,
    const float* __restrict__ w_data, const float* __restrict__ b_data,
    float2* __restrict__ kv_i, float2* __restrict__ kv_d,
    float* __restrict__ q_glob)
{
    int tid  = threadIdx.x;
    int wave = tid >> 6, lane = tid & 63;
    int grp  = lane >> 4, l = lane & 15;
    int g    = blockIdx.x * 16 + wave * 4 + grp;   // group id, 2 rows each
    int row0 = g * 2;                              // 0..2N-1, side-uniform
    int side = (row0 >= Nc) ? 1 : 0;
    int node0 = row0 - side * Nc;
    const float* x  = side ? x_data : x_inst;
    const float* w  = side ? w_data : w_inst;
    const float* bp = side ? b_data : b_inst;
    float2* kv = side ? kv_d : kv_i;

    float wr[48];
#pragma unroll
    for (int it = 0; it < 4; ++it) {
        const float4* wv = (const float4*)(w + (it * 64 + l * 4) * 3);
        float4 f0 = wv[0], f1 = wv[1], f2 = wv[2];
        wr[it*12+0]=f0.x; wr[it*12+1]=f0.y; wr[it*12+2]=f0.z; wr[it*12+3]=f0.w;
        wr[it*12+4]=f1.x; wr[it*12+5]=f1.y; wr[it*12+6]=f1.z; wr[it*12+7]=f1.w;
        wr[it*12+8]=f2.x; wr[it*12+9]=f2.y; wr[it*12+10]=f2.z; wr[it*12+11]=f2.w;
    }
    float b0 = bp[0], b1 = bp[1], b2 = bp[2];

    const float4* rp = (const float4*)(x + (size_t)node0 * Cc);
    // issue all 8 loads up front (2 rows x 4 float4)
    float4 xv[2][4];
#pragma unroll
    for (int r = 0; r < 2; ++r)
#pragma unroll
        for (int it = 0; it < 4; ++it)
            xv[r][it] = rp[r * 64 + it * 16 + l];

#pragma unroll
    for (int r = 0; r < 2; ++r) {
        float kk = 0.f, qq = 0.f, vv = 0.f;
#pragma unroll
        for (int it = 0; it < 4; ++it) {
            float xs[4] = {xv[r][it].x, xv[r][it].y, xv[r][it].z, xv[r][it].w};
#pragma unroll
            for (int u = 0; u < 4; ++u) {
                float xd = xs[u];
                kk = fmaf(xd, wr[it * 12 + u * 3 + 0], kk);
                qq = fmaf(xd, wr[it * 12 + u * 3 + 1], qq);
                vv = fmaf(xd, wr[it * 12 + u * 3 + 2], vv);
            }
        }
#pragma unroll
        for (int off = 8; off; off >>= 1) {
            kk += __shfl_xor(kk, off, 64);
            qq += __shfl_xor(qq, off, 64);
            vv += __shfl_xor(vv, off, 64);
        }
        if (l == 0) {
            int node = node0 + r;
            kv[node] = make_float2(kk + b0, vv + b2);
            q_glob[side * Nc + node] = qq + b1;
        }
    }
}

// ---------- kernel 2a: per-bucket edge counts (int4 loads) ----------
__global__ __launch_bounds__(256) void count_kernel(
    const int* __restrict__ ei0, const int* __restrict__ ei1,
    const int* __restrict__ ei2, unsigned* __restrict__ bucket_cnt)
{
    __shared__ unsigned hist[NBUK];
    int tid = threadIdx.x;
    for (int j = tid; j < NBUK; j += 256) hist[j] = 0;
    __syncthreads();
    unsigned base = blockIdx.x * (unsigned)CHUNK;
    int t = (int)(base >> 20);
    unsigned i0 = base & (unsigned)(Ec - 1);
    const int* ei = (t == 0) ? ei0 : (t == 1) ? ei1 : ei2;
    int off = (t == 0) ? Nc : 0;
    const int4* dv = (const int4*)(ei + Ec + i0);
#pragma unroll 4
    for (int j = 0; j < CHUNK / 1024; ++j) {
        int4 d4 = dv[j * 256 + tid];
        atomicAdd(&hist[(unsigned)(d4.x + off) >> 7], 1u);
        atomicAdd(&hist[(unsigned)(d4.y + off) >> 7], 1u);
        atomicAdd(&hist[(unsigned)(d4.z + off) >> 7], 1u);
        atomicAdd(&hist[(unsigned)(d4.w + off) >> 7], 1u);
    }
    __syncthreads();
    for (int j = tid; j < NBUK; j += 256)
        if (hist[j]) atomicAdd(&bucket_cnt[j], hist[j]);
}

// ---------- kernel 2b: exclusive scan of bucket counts ----------
__global__ __launch_bounds__(1024) void scan_kernel(
    const unsigned* __restrict__ bucket_cnt,
    unsigned* __restrict__ bucket_base, unsigned* __restrict__ bucket_fill)
{
    __shared__ unsigned s[NBUK];
    int t = threadIdx.x;
    unsigned mine = bucket_cnt[t];
    s[t] = mine;
    __syncthreads();
    for (int off = 1; off < NBUK; off <<= 1) {
        unsigned v = (t >= off) ? s[t - off] : 0u;
        __syncthreads();
        s[t] += v;
        __syncthreads();
    }
    unsigned ex = s[t] - mine;
    bucket_base[t] = ex;
    bucket_fill[t] = ex;
    if (t == NBUK - 1) bucket_base[NBUK] = s[t];
}

// ---------- kernel 2c: scatter packed records into bucket order ----------
// record = s(16 bits) | t<<16 | (dg&127)<<18
__global__ __launch_bounds__(256) void fill_kernel(
    const int* __restrict__ ei0, const int* __restrict__ ei1,
    const int* __restrict__ ei2, unsigned* __restrict__ bucket_fill,
    unsigned* __restrict__ sorted)
{
    __shared__ unsigned hist[NBUK];
    __shared__ unsigned res[NBUK];
    int tid = threadIdx.x;
    for (int j = tid; j < NBUK; j += 256) hist[j] = 0;
    __syncthreads();
    unsigned base = blockIdx.x * (unsigned)CHUNK;
    int t = (int)(base >> 20);
    unsigned i0 = base & (unsigned)(Ec - 1);
    const int* ei = (t == 0) ? ei0 : (t == 1) ? ei1 : ei2;
    int off = (t == 0) ? Nc : 0;
    const int4* dv = (const int4*)(ei + Ec + i0);
    const int4* sv = (const int4*)(ei + i0);
#pragma unroll 4
    for (int j = 0; j < CHUNK / 1024; ++j) {
        int4 d4 = dv[j * 256 + tid];
        atomicAdd(&hist[(unsigned)(d4.x + off) >> 7], 1u);
        atomicAdd(&hist[(unsigned)(d4.y + off) >> 7], 1u);
        atomicAdd(&hist[(unsigned)(d4.z + off) >> 7], 1u);
        atomicAdd(&hist[(unsigned)(d4.w + off) >> 7], 1u);
    }
    __syncthreads();
    for (int j = tid; j < NBUK; j += 256) {
        unsigned h = hist[j];
        res[j] = h ? atomicAdd(&bucket_fill[j], h) : 0u;
        hist[j] = 0;           // reuse as local fill counter
    }
    __syncthreads();
#pragma unroll 4
    for (int j = 0; j < CHUNK / 1024; ++j) {
        int4 d4 = dv[j * 256 + tid];
        int4 s4 = sv[j * 256 + tid];
        int dd[4] = {d4.x, d4.y, d4.z, d4.w};
        int ss[4] = {s4.x, s4.y, s4.z, s4.w};
#pragma unroll
        for (int u = 0; u < 4; ++u) {
            int dg  = dd[u] + off;
            int bkt = dg >> 7;
            unsigned local = atomicAdd(&hist[bkt], 1u);
            sorted[res[bkt] + local] =
                (unsigned)ss[u] | ((unsigned)t << 16) | ((unsigned)(dg & 127) << 18);
        }
    }
}

// ---------- kernel 2d: per-bucket LDS accumulation (fp32, hw exp) ----------
__global__ __launch_bounds__(256) void bucket_accum_kernel(
    const unsigned* __restrict__ bucket_base, const unsigned* __restrict__ sorted,
    const float* __restrict__ krel_w, const float* __restrict__ krel_b,
    const float* __restrict__ vrel_w, const float* __restrict__ vrel_b,
    const float* __restrict__ p_rel,
    const float2* __restrict__ kv_i, const float2* __restrict__ kv_d,
    const float* __restrict__ q_glob,
    float* __restrict__ den, float* __restrict__ num)
{
    __shared__ float den_l[BUKW];
    __shared__ float num_l[BUKW];
    __shared__ float q_l[BUKW];
    int tid = threadIdx.x;
    int b   = blockIdx.x;
    if (tid < BUKW) {
        den_l[tid] = 0.0f;
        num_l[tid] = 0.0f;
        q_l[tid]   = q_glob[b * BUKW + tid];
    }
    float kw0 = krel_w[0], kw1 = krel_w[1], kw2 = krel_w[2];
    float kb0 = krel_b[0], kb1 = krel_b[1], kb2 = krel_b[2];
    float vw0 = vrel_w[0], vw1 = vrel_w[1], vw2 = vrel_w[2];
    float vb0 = vrel_b[0], vb1 = vrel_b[1], vb2 = vrel_b[2];
    float pr0 = p_rel[0],  pr1 = p_rel[1],  pr2 = p_rel[2];
    unsigned beg = bucket_base[b], end = bucket_base[b + 1];
    __syncthreads();

    for (unsigned e = beg + tid; e < end; e += 256) {
        unsigned r = sorted[e];
        int s    = (int)(r & 0xFFFFu);
        int t    = (int)((r >> 16) & 3u);
        int low7 = (int)((r >> 18) & 127u);
        float2 kvv = (t == 1) ? kv_d[s] : kv_i[s];
        float kwt = (t == 0) ? kw0 : (t == 1) ? kw1 : kw2;
        float kbt = (t == 0) ? kb0 : (t == 1) ? kb1 : kb2;
        float vwt = (t == 0) ? vw0 : (t == 1) ? vw1 : vw2;
        float vbt = (t == 0) ? vb0 : (t == 1) ? vb1 : vb2;
        float prt = (t == 0) ? pr0 : (t == 1) ? pr1 : pr2;
        float ke = fmaf(kvv.x, kwt, kbt);
        float ve = fmaf(kvv.y, vwt, vbt);
        float logit = q_l[low7] * ke * prt;
        float ex = __expf(fminf(logit, 80.0f));  // clamp: fp32-overflow insurance
        __hip_atomic_fetch_add(&den_l[low7], ex, __ATOMIC_RELAXED,
                               __HIP_MEMORY_SCOPE_WORKGROUP);
        __hip_atomic_fetch_add(&num_l[low7], ex * ve, __ATOMIC_RELAXED,
                               __HIP_MEMORY_SCOPE_WORKGROUP);
    }
    __syncthreads();
    if (tid < BUKW) {
        den[b * BUKW + tid] = den_l[tid];   // plain stores
        num[b * BUKW + tid] = num_l[tid];
    }
}

// ---------- kernel 3: score + 2-level radix top-K (u32 keys) ----------
__global__ __launch_bounds__(1024) void select_kernel(
    const float* __restrict__ den, const float* __restrict__ num,
    const float* __restrict__ w_out_inst, const float* __restrict__ b_out_inst,
    const float* __restrict__ w_out_data, const float* __restrict__ b_out_data,
    int* __restrict__ sel_idx, float* __restrict__ sel_w)
{
    __shared__ unsigned keys[NPGc];             // 16 KB
    __shared__ unsigned hist[2048];             // 8 KB
    __shared__ unsigned wsum[16];
    __shared__ unsigned short cand[NPGc];       // 8 KB
    __shared__ unsigned sh_bin1, sh_rem1, sh_bin2, sh_rem2, sh_cnt, sh_nc;

    int tid  = threadIdx.x;
    int seg  = blockIdx.x;          // 0..31
    int side = seg >> 4;
    int b    = seg & 15;
    float wo = side ? w_out_data[0] : w_out_inst[0];
    float bo = side ? b_out_data[0] : b_out_inst[0];
    int base_node = side * Nc + b * NPGc;
    int base_sel  = seg * Kc;

    // phase 0: scores -> keys (4 per thread, coalesced)
    unsigned myk[4]; int myj[4];
#pragma unroll
    for (int p = 0; p < 4; ++p) {
        int j = p * 1024 + tid;
        float dn = den[base_node + j];
        float a  = (dn > 0.0f) ? num[base_node + j] / dn : 0.0f;
        float z  = fmaf(a, wo, bo);
        float s  = 0.5f * z * (1.0f + erff(z * 0.70710678f));
        unsigned k32 = fkey(s);
        keys[j] = k32; myk[p] = k32; myj[p] = j;
    }
    if (tid == 0) { sh_cnt = 0; sh_nc = 0; }
    hist[tid] = 0; hist[tid + 1024] = 0;
    __syncthreads();

    // phase 1: hist over bits [31:21]
#pragma unroll
    for (int p = 0; p < 4; ++p) atomicAdd(&hist[myk[p] >> 21], 1u);
    __syncthreads();
    {   // suffix scan (descending bins): thread owns bins {2047-2t, 2046-2t}
        unsigned g0 = hist[2047 - 2 * tid];
        unsigned g1 = hist[2046 - 2 * tid];
        unsigned x = g0 + g1;
        int lane = tid & 63;
#pragma unroll
        for (int off = 1; off < 64; off <<= 1) {
            unsigned y = __shfl_up(x, off, 64);
            if (lane >= off) x += y;
        }
        if (lane == 63) wsum[tid >> 6] = x;
        __syncthreads();
        if (tid < 16) {
            unsigned v = wsum[tid];
#pragma unroll
            for (int off = 1; off < 16; off <<= 1) {
                unsigned y = __shfl_up(v, off, 64);
                if (tid >= off) v += y;
            }
            wsum[tid] = v;
        }
        __syncthreads();
        unsigned basew = (tid >= 64) ? wsum[(tid >> 6) - 1] : 0u;
        unsigned incl  = basew + x;        // suffix-incl at bin 2046-2t
        unsigned incl0 = incl - g1;        // suffix-incl at bin 2047-2t
        unsigned K = Kc;
        if (incl0 >= K && incl0 - g0 < K) { sh_bin1 = 2047 - 2 * tid; sh_rem1 = K - (incl0 - g0); }
        if (incl  >= K && incl0     < K) { sh_bin1 = 2046 - 2 * tid; sh_rem1 = K - incl0; }
    }
    __syncthreads();
    unsigned bin1 = sh_bin1, rem1 = sh_rem1;
    hist[tid] = 0; hist[tid + 1024] = 0;
    __syncthreads();

    // phase 2: hist over bits [20:10] among bin1 keys
#pragma unroll
    for (int p = 0; p < 4; ++p)
        if ((myk[p] >> 21) == bin1)
            atomicAdd(&hist[(myk[p] >> 10) & 2047u], 1u);
    __syncthreads();
    {
        unsigned g0 = hist[2047 - 2 * tid];
        unsigned g1 = hist[2046 - 2 * tid];
        unsigned x = g0 + g1;
        int lane = tid & 63;
#pragma unroll
        for (int off = 1; off < 64; off <<= 1) {
            unsigned y = __shfl_up(x, off, 64);
            if (lane >= off) x += y;
        }
        if (lane == 63) wsum[tid >> 6] = x;
        __syncthreads();
        if (tid < 16) {
            unsigned v = wsum[tid];
#pragma unroll
            for (int off = 1; off < 16; off <<= 1) {
                unsigned y = __shfl_up(v, off, 64);
                if (tid >= off) v += y;
            }
            wsum[tid] = v;
        }
        __syncthreads();
        unsigned basew = (tid >= 64) ? wsum[(tid >> 6) - 1] : 0u;
        unsigned incl  = basew + x;
        unsigned incl0 = incl - g1;
        unsigned K = rem1;
        if (incl0 >= K && incl0 - g0 < K) { sh_bin2 = 2047 - 2 * tid; sh_rem2 = K - (incl0 - g0); }
        if (incl  >= K && incl0     < K) { sh_bin2 = 2046 - 2 * tid; sh_rem2 = K - incl0; }
    }
    __syncthreads();
    unsigned pref22 = (bin1 << 11) | sh_bin2;
    unsigned rem2 = sh_rem2;

    // phase 3: classify
#pragma unroll
    for (int p = 0; p < 4; ++p) {
        unsigned top22 = myk[p] >> 10;
        if (top22 > pref22) {
            unsigned pos = atomicAdd(&sh_cnt, 1u);
            sel_idx[base_sel + pos] = myj[p];
            sel_w[base_sel + pos]   = tanhf(inv_fkey(myk[p]));
        } else if (top22 == pref22) {
            unsigned cp = atomicAdd(&sh_nc, 1u);
            cand[cp] = (unsigned short)myj[p];
        }
    }
    __syncthreads();

    // phase 4: exact rank among candidates (key desc, index asc)
    unsigned nc = sh_nc;
    for (unsigned c = tid; c < nc; c += 1024) {
        int j = cand[c];
        unsigned k32 = keys[j];
        unsigned rank = 0;
        for (unsigned q = 0; q < nc; ++q) {
            int jq = cand[q];
            unsigned kq = keys[jq];
            rank += (kq > k32 || (kq == k32 && jq < j)) ? 1u : 0u;
        }
        if (rank < rem2) {
            unsigned pos = atomicAdd(&sh_cnt, 1u);
            sel_idx[base_sel + pos] = j;
            sel_w[base_sel + pos]   = tanhf(inv_fkey(k32));
        }
    }
}

// ---------- kernel 4: weighted mean of selected rows ----------
// 32 segs x 16 chunks of 64 rows = 512 blocks; 1024 threads = 16 waves;
// each wave does 4 rows (16*4 = 64).
__global__ __launch_bounds__(1024) void pool_kernel(
    const float* __restrict__ x_inst, const float* __restrict__ x_data,
    const int* __restrict__ sel_idx, const float* __restrict__ sel_w,
    float* __restrict__ out)
{
    __shared__ int   ridx[64];
    __shared__ float rw[64];
    __shared__ float accs[256];
    int tid   = threadIdx.x;
    int blk   = blockIdx.x;
    int seg   = blk >> 4;
    int chunk = blk & 15;
    int side  = seg >> 4;
    int b     = seg & 15;
    if (tid < 64) {
        ridx[tid] = sel_idx[seg * Kc + chunk * 64 + tid];
        rw[tid]   = sel_w[seg * Kc + chunk * 64 + tid];
    }
    if (tid < 256) accs[tid] = 0.0f;
    __syncthreads();
    const float* x = side ? x_data : x_inst;
    int w = tid >> 6, l = tid & 63;
    float ax = 0.f, ay = 0.f, az = 0.f, aw = 0.f;
#pragma unroll
    for (int r = 0; r < 4; ++r) {
        int   row = ridx[w * 4 + r];
        float wt  = rw[w * 4 + r];
        float4 xv = ((const float4*)(x + ((size_t)(b * NPGc + row)) * Cc))[l];
        ax = fmaf(xv.x, wt, ax); ay = fmaf(xv.y, wt, ay);
        az = fmaf(xv.z, wt, az); aw = fmaf(xv.w, wt, aw);
    }
    atomicAdd(&accs[l * 4 + 0], ax);
    atomicAdd(&accs[l * 4 + 1], ay);
    atomicAdd(&accs[l * 4 + 2], az);
    atomicAdd(&accs[l * 4 + 3], aw);
    __syncthreads();
    if (tid < 256)
        unsafeAtomicAdd(&out[b * 512 + side * 256 + tid], accs[tid] * (1.0f / (float)Kc));
}

extern "C" void kernel_launch(void* const* d_in, const int* in_sizes, int n_in,
                              void* d_out, int out_size, void* d_ws, size_t ws_size,
                              hipStream_t stream) {
    const float* x_inst     = (const float*)d_in[0];
    const float* x_data     = (const float*)d_in[1];
    const float* w_kqv_inst = (const float*)d_in[2];
    const float* b_kqv_inst = (const float*)d_in[3];
    const float* w_kqv_data = (const float*)d_in[4];
    const float* b_kqv_data = (const float*)d_in[5];
    const float* w_out_inst = (const float*)d_in[6];
    const float* b_out_inst = (const float*)d_in[7];
    const float* w_out_data = (const float*)d_in[8];
    const float* b_out_data = (const float*)d_in[9];
    const float* krel_w     = (const float*)d_in[10];
    const float* krel_b     = (const float*)d_in[11];
    const float* vrel_w     = (const float*)d_in[12];
    const float* vrel_b     = (const float*)d_in[13];
    const float* p_rel      = (const float*)d_in[14];
    const int*   ei_i2d     = (const int*)d_in[15];
    const int*   ei_d2i     = (const int*)d_in[16];
    const int*   ei_i2i     = (const int*)d_in[17];
    float* out = (float*)d_out;

    // workspace layout (fp32)
    char* ws = (char*)d_ws;
    float2* kv_i   = (float2*)ws;                        // N
    float2* kv_d   = kv_i + Nc;                          // N
    float*  q_glob = (float*)(kv_d + Nc);                // 2N
    float*  den    = q_glob + 2 * Nc;                    // 2N
    float*  num    = den + 2 * Nc;                       // 2N
    unsigned* bucket_cnt  = (unsigned*)(num + 2 * Nc);   // NBUK
    unsigned* bucket_base = bucket_cnt + NBUK;           // NBUK+1
    unsigned* bucket_fill = bucket_base + NBUK + 1;      // NBUK
    int*      sel_idx     = (int*)(bucket_fill + NBUK);  // 32*K
    float*    sel_w       = (float*)(sel_idx + 32 * Kc); // 32*K
    unsigned* sorted      = (unsigned*)(sel_w + 32 * Kc);// 3E (12.6 MB)

    hipMemsetAsync(bucket_cnt, 0, NBUK * sizeof(unsigned), stream);
    hipMemsetAsync(d_out, 0, (size_t)out_size * sizeof(float), stream);

    // edge path (independent of x): count -> scan -> fill
    count_kernel<<<NCHUNK, 256, 0, stream>>>(ei_i2d, ei_d2i, ei_i2i, bucket_cnt);
    scan_kernel<<<1, NBUK, 0, stream>>>(bucket_cnt, bucket_base, bucket_fill);
    fill_kernel<<<NCHUNK, 256, 0, stream>>>(ei_i2d, ei_d2i, ei_i2i,
                                            bucket_fill, sorted);

    // kqv for both sides: 32 rows per block, 4096 blocks
    kqv_kernel<<<(2 * Nc) / 32, 256, 0, stream>>>(
        x_inst, x_data, w_kqv_inst, b_kqv_inst, w_kqv_data, b_kqv_data,
        kv_i, kv_d, q_glob);

    // per-bucket LDS accumulate
    bucket_accum_kernel<<<NBUK, 256, 0, stream>>>(
        bucket_base, sorted,
        krel_w, krel_b, vrel_w, vrel_b, p_rel,
        kv_i, kv_d, q_glob, den, num);

    // score + top-K select
    select_kernel<<<32, 1024, 0, stream>>>(
        den, num, w_out_inst, b_out_inst, w_out_data, b_out_data,
        sel_idx, sel_w);

    // pooled weighted mean
    pool_kernel<<<512, 1024, 0, stream>>>(x_inst, x_data, sel_idx, sel_w, out);
}

// Round 7
// 307.264 us; speedup vs baseline: 1.9924x; 1.0411x over previous
//
#include <hip/hip_runtime.h>
#include <math.h>

// Problem constants
constexpr int BB   = 16;
constexpr int NPGc = 4096;
constexpr int Cc   = 256;
constexpr int Nc   = BB * NPGc;      // 65536
constexpr int Ec   = Nc * 16;        // 1048576 = 1<<20
constexpr int Kc   = 1024;           // ceil(0.25*4096)
constexpr int NBUK = 512;            // dst buckets
constexpr int BUKW = 256;            // dst per bucket (2N / NBUK)
constexpr int CHUNK = 8192;          // edges per count/fill block
constexpr int NCHUNK = (3 * Ec) / CHUNK;   // 384

// ---------- monotonic float <-> u32 key ----------
__device__ __forceinline__ unsigned fkey(float f) {
    int b = __float_as_int(f);
    unsigned u = (unsigned)b;
    return (b < 0) ? ~u : (u | 0x80000000u);
}
__device__ __forceinline__ float inv_fkey(unsigned u) {
    unsigned b = (u & 0x80000000u) ? (u ^ 0x80000000u) : ~u;
    return __int_as_float((int)b);
}

// ---------- kernel 1: kqv = x @ w + b (fp32) ----------
__global__ __launch_bounds__(256) void kqv_kernel(
    const float* __restrict__ x_inst, const float* __restrict__ x_data,
    const float* __restrict__ w_inst, const float* __restrict__ b_inst,
    const float* __restrict__ w_data, const float* __restrict__ b_data,
    float2* __restrict__ kv_i, float2* __restrict__ kv_d,
    float* __restrict__ q_glob)
{
    int tid  = threadIdx.x;
    int wave = tid >> 6, lane = tid & 63;
    int grp  = lane >> 4, l = lane & 15;
    int g    = blockIdx.x * 16 + wave * 4 + grp;   // group id, 2 rows each
    int row0 = g * 2;                              // 0..2N-1, side-uniform
    int side = (row0 >= Nc) ? 1 : 0;
    int node0 = row0 - side * Nc;
    const float* x  = side ? x_data : x_inst;
    const float* w  = side ? w_data : w_inst;
    const float* bp = side ? b_data : b_inst;
    float2* kv = side ? kv_d : kv_i;

    float wr[48];
#pragma unroll
    for (int it = 0; it < 4; ++it) {
        const float4* wv = (const float4*)(w + (it * 64 + l * 4) * 3);
        float4 f0 = wv[0], f1 = wv[1], f2 = wv[2];
        wr[it*12+0]=f0.x; wr[it*12+1]=f0.y; wr[it*12+2]=f0.z; wr[it*12+3]=f0.w;
        wr[it*12+4]=f1.x; wr[it*12+5]=f1.y; wr[it*12+6]=f1.z; wr[it*12+7]=f1.w;
        wr[it*12+8]=f2.x; wr[it*12+9]=f2.y; wr[it*12+10]=f2.z; wr[it*12+11]=f2.w;
    }
    float b0 = bp[0], b1 = bp[1], b2 = bp[2];

    const float4* rp = (const float4*)(x + (size_t)node0 * Cc);
    float4 xv[2][4];
#pragma unroll
    for (int r = 0; r < 2; ++r)
#pragma unroll
        for (int it = 0; it < 4; ++it)
            xv[r][it] = rp[r * 64 + it * 16 + l];

#pragma unroll
    for (int r = 0; r < 2; ++r) {
        float kk = 0.f, qq = 0.f, vv = 0.f;
#pragma unroll
        for (int it = 0; it < 4; ++it) {
            float xs[4] = {xv[r][it].x, xv[r][it].y, xv[r][it].z, xv[r][it].w};
#pragma unroll
            for (int u = 0; u < 4; ++u) {
                float xd = xs[u];
                kk = fmaf(xd, wr[it * 12 + u * 3 + 0], kk);
                qq = fmaf(xd, wr[it * 12 + u * 3 + 1], qq);
                vv = fmaf(xd, wr[it * 12 + u * 3 + 2], vv);
            }
        }
#pragma unroll
        for (int off = 8; off; off >>= 1) {
            kk += __shfl_xor(kk, off, 64);
            qq += __shfl_xor(qq, off, 64);
            vv += __shfl_xor(vv, off, 64);
        }
        if (l == 0) {
            int node = node0 + r;
            kv[node] = make_float2(kk + b0, vv + b2);
            q_glob[side * Nc + node] = qq + b1;
        }
    }
}

// ---------- kernel 2a: per-bucket edge counts (int4 loads) ----------
__global__ __launch_bounds__(256) void count_kernel(
    const int* __restrict__ ei0, const int* __restrict__ ei1,
    const int* __restrict__ ei2, unsigned* __restrict__ bucket_cnt)
{
    __shared__ unsigned hist[NBUK];
    int tid = threadIdx.x;
    for (int j = tid; j < NBUK; j += 256) hist[j] = 0;
    __syncthreads();
    unsigned base = blockIdx.x * (unsigned)CHUNK;
    int t = (int)(base >> 20);
    unsigned i0 = base & (unsigned)(Ec - 1);
    const int* ei = (t == 0) ? ei0 : (t == 1) ? ei1 : ei2;
    int off = (t == 0) ? Nc : 0;
    const int4* dv = (const int4*)(ei + Ec + i0);
#pragma unroll 4
    for (int j = 0; j < CHUNK / 1024; ++j) {
        int4 d4 = dv[j * 256 + tid];
        atomicAdd(&hist[(unsigned)(d4.x + off) >> 8], 1u);
        atomicAdd(&hist[(unsigned)(d4.y + off) >> 8], 1u);
        atomicAdd(&hist[(unsigned)(d4.z + off) >> 8], 1u);
        atomicAdd(&hist[(unsigned)(d4.w + off) >> 8], 1u);
    }
    __syncthreads();
    for (int j = tid; j < NBUK; j += 256)
        if (hist[j]) atomicAdd(&bucket_cnt[j], hist[j]);
}

// ---------- kernel 2b: exclusive scan of bucket counts ----------
__global__ __launch_bounds__(NBUK) void scan_kernel(
    const unsigned* __restrict__ bucket_cnt,
    unsigned* __restrict__ bucket_base, unsigned* __restrict__ bucket_fill)
{
    __shared__ unsigned s[NBUK];
    int t = threadIdx.x;
    unsigned mine = bucket_cnt[t];
    s[t] = mine;
    __syncthreads();
    for (int off = 1; off < NBUK; off <<= 1) {
        unsigned v = (t >= off) ? s[t - off] : 0u;
        __syncthreads();
        s[t] += v;
        __syncthreads();
    }
    unsigned ex = s[t] - mine;
    bucket_base[t] = ex;
    bucket_fill[t] = ex;
    if (t == NBUK - 1) bucket_base[NBUK] = s[t];
}

// ---------- kernel 2c: scatter packed records into bucket order ----------
// record = s(16 bits) | t<<16 | (dg&255)<<18
__global__ __launch_bounds__(256) void fill_kernel(
    const int* __restrict__ ei0, const int* __restrict__ ei1,
    const int* __restrict__ ei2, unsigned* __restrict__ bucket_fill,
    unsigned* __restrict__ sorted)
{
    __shared__ unsigned hist[NBUK];
    __shared__ unsigned res[NBUK];
    int tid = threadIdx.x;
    for (int j = tid; j < NBUK; j += 256) hist[j] = 0;
    __syncthreads();
    unsigned base = blockIdx.x * (unsigned)CHUNK;
    int t = (int)(base >> 20);
    unsigned i0 = base & (unsigned)(Ec - 1);
    const int* ei = (t == 0) ? ei0 : (t == 1) ? ei1 : ei2;
    int off = (t == 0) ? Nc : 0;
    const int4* dv = (const int4*)(ei + Ec + i0);
    const int4* sv = (const int4*)(ei + i0);
#pragma unroll 4
    for (int j = 0; j < CHUNK / 1024; ++j) {
        int4 d4 = dv[j * 256 + tid];
        atomicAdd(&hist[(unsigned)(d4.x + off) >> 8], 1u);
        atomicAdd(&hist[(unsigned)(d4.y + off) >> 8], 1u);
        atomicAdd(&hist[(unsigned)(d4.z + off) >> 8], 1u);
        atomicAdd(&hist[(unsigned)(d4.w + off) >> 8], 1u);
    }
    __syncthreads();
    for (int j = tid; j < NBUK; j += 256) {
        unsigned h = hist[j];
        // res = absolute base slot for this block's run in bucket j
        res[j] = h ? atomicAdd(&bucket_fill[j], h) : 0u;
    }
    __syncthreads();
#pragma unroll 4
    for (int j = 0; j < CHUNK / 1024; ++j) {
        int4 d4 = dv[j * 256 + tid];
        int4 s4 = sv[j * 256 + tid];
        int dd[4] = {d4.x, d4.y, d4.z, d4.w};
        int ss[4] = {s4.x, s4.y, s4.z, s4.w};
#pragma unroll
        for (int u = 0; u < 4; ++u) {
            int dg  = dd[u] + off;
            int bkt = dg >> 8;
            unsigned pos = atomicAdd(&res[bkt], 1u);  // returning LDS atomic
            sorted[pos] =
                (unsigned)ss[u] | ((unsigned)t << 16) | ((unsigned)(dg & 255) << 18);
        }
    }
}

// ---------- kernel 2d: per-bucket LDS accumulation (fp32, 2x replicated) ----------
__global__ __launch_bounds__(512) void bucket_accum_kernel(
    const unsigned* __restrict__ bucket_base, const unsigned* __restrict__ sorted,
    const float* __restrict__ krel_w, const float* __restrict__ krel_b,
    const float* __restrict__ vrel_w, const float* __restrict__ vrel_b,
    const float* __restrict__ p_rel,
    const float2* __restrict__ kv_i, const float2* __restrict__ kv_d,
    const float* __restrict__ q_glob,
    float* __restrict__ den, float* __restrict__ num)
{
    __shared__ float den_l[2 * BUKW];   // [dst][rep] interleaved: adjacent banks
    __shared__ float num_l[2 * BUKW];
    __shared__ float q_l[BUKW];
    int tid = threadIdx.x;
    int b   = blockIdx.x;
    den_l[tid] = 0.0f; num_l[tid] = 0.0f;      // 512 entries each
    if (tid < BUKW) q_l[tid] = q_glob[b * BUKW + tid];
    float kw0 = krel_w[0], kw1 = krel_w[1], kw2 = krel_w[2];
    float kb0 = krel_b[0], kb1 = krel_b[1], kb2 = krel_b[2];
    float vw0 = vrel_w[0], vw1 = vrel_w[1], vw2 = vrel_w[2];
    float vb0 = vrel_b[0], vb1 = vrel_b[1], vb2 = vrel_b[2];
    float pr0 = p_rel[0],  pr1 = p_rel[1],  pr2 = p_rel[2];
    unsigned beg = bucket_base[b], end = bucket_base[b + 1];
    int rep = tid & 1;
    __syncthreads();

    for (unsigned e = beg + tid; e < end; e += 512) {
        unsigned r = sorted[e];
        int s    = (int)(r & 0xFFFFu);
        int t    = (int)((r >> 16) & 3u);
        int low8 = (int)((r >> 18) & 255u);
        float2 kvv = (t == 1) ? kv_d[s] : kv_i[s];
        float kwt = (t == 0) ? kw0 : (t == 1) ? kw1 : kw2;
        float kbt = (t == 0) ? kb0 : (t == 1) ? kb1 : kb2;
        float vwt = (t == 0) ? vw0 : (t == 1) ? vw1 : vw2;
        float vbt = (t == 0) ? vb0 : (t == 1) ? vb1 : vb2;
        float prt = (t == 0) ? pr0 : (t == 1) ? pr1 : pr2;
        float ke = fmaf(kvv.x, kwt, kbt);
        float ve = fmaf(kvv.y, vwt, vbt);
        float logit = q_l[low8] * ke * prt;
        float ex = __expf(fminf(logit, 80.0f));
        int slot = low8 * 2 + rep;
        __hip_atomic_fetch_add(&den_l[slot], ex, __ATOMIC_RELAXED,
                               __HIP_MEMORY_SCOPE_WORKGROUP);
        __hip_atomic_fetch_add(&num_l[slot], ex * ve, __ATOMIC_RELAXED,
                               __HIP_MEMORY_SCOPE_WORKGROUP);
    }
    __syncthreads();
    if (tid < BUKW) {
        den[b * BUKW + tid] = den_l[tid * 2] + den_l[tid * 2 + 1];
        num[b * BUKW + tid] = num_l[tid * 2] + num_l[tid * 2 + 1];
    }
}

// ---------- kernel 3: score + 2-level radix top-K (u32 keys) ----------
__global__ __launch_bounds__(1024) void select_kernel(
    const float* __restrict__ den, const float* __restrict__ num,
    const float* __restrict__ w_out_inst, const float* __restrict__ b_out_inst,
    const float* __restrict__ w_out_data, const float* __restrict__ b_out_data,
    int* __restrict__ sel_idx, float* __restrict__ sel_w)
{
    __shared__ unsigned keys[NPGc];             // 16 KB
    __shared__ unsigned hist[2048];             // 8 KB
    __shared__ unsigned wsum[16];
    __shared__ unsigned short cand[NPGc];       // 8 KB
    __shared__ unsigned sh_bin1, sh_rem1, sh_bin2, sh_rem2, sh_cnt, sh_nc;

    int tid  = threadIdx.x;
    int seg  = blockIdx.x;          // 0..31
    int side = seg >> 4;
    int b    = seg & 15;
    float wo = side ? w_out_data[0] : w_out_inst[0];
    float bo = side ? b_out_data[0] : b_out_inst[0];
    int base_node = side * Nc + b * NPGc;
    int base_sel  = seg * Kc;

    unsigned myk[4]; int myj[4];
#pragma unroll
    for (int p = 0; p < 4; ++p) {
        int j = p * 1024 + tid;
        float dn = den[base_node + j];
        float a  = (dn > 0.0f) ? num[base_node + j] / dn : 0.0f;
        float z  = fmaf(a, wo, bo);
        float s  = 0.5f * z * (1.0f + erff(z * 0.70710678f));
        unsigned k32 = fkey(s);
        keys[j] = k32; myk[p] = k32; myj[p] = j;
    }
    if (tid == 0) { sh_cnt = 0; sh_nc = 0; }
    hist[tid] = 0; hist[tid + 1024] = 0;
    __syncthreads();

    // phase 1: hist over bits [31:21]
#pragma unroll
    for (int p = 0; p < 4; ++p) atomicAdd(&hist[myk[p] >> 21], 1u);
    __syncthreads();
    {
        unsigned g0 = hist[2047 - 2 * tid];
        unsigned g1 = hist[2046 - 2 * tid];
        unsigned x = g0 + g1;
        int lane = tid & 63;
#pragma unroll
        for (int off = 1; off < 64; off <<= 1) {
            unsigned y = __shfl_up(x, off, 64);
            if (lane >= off) x += y;
        }
        if (lane == 63) wsum[tid >> 6] = x;
        __syncthreads();
        if (tid < 16) {
            unsigned v = wsum[tid];
#pragma unroll
            for (int off = 1; off < 16; off <<= 1) {
                unsigned y = __shfl_up(v, off, 64);
                if (tid >= off) v += y;
            }
            wsum[tid] = v;
        }
        __syncthreads();
        unsigned basew = (tid >= 64) ? wsum[(tid >> 6) - 1] : 0u;
        unsigned incl  = basew + x;
        unsigned incl0 = incl - g1;
        unsigned K = Kc;
        if (incl0 >= K && incl0 - g0 < K) { sh_bin1 = 2047 - 2 * tid; sh_rem1 = K - (incl0 - g0); }
        if (incl  >= K && incl0     < K) { sh_bin1 = 2046 - 2 * tid; sh_rem1 = K - incl0; }
    }
    __syncthreads();
    unsigned bin1 = sh_bin1, rem1 = sh_rem1;
    hist[tid] = 0; hist[tid + 1024] = 0;
    __syncthreads();

    // phase 2: hist over bits [20:10] among bin1 keys
#pragma unroll
    for (int p = 0; p < 4; ++p)
        if ((myk[p] >> 21) == bin1)
            atomicAdd(&hist[(myk[p] >> 10) & 2047u], 1u);
    __syncthreads();
    {
        unsigned g0 = hist[2047 - 2 * tid];
        unsigned g1 = hist[2046 - 2 * tid];
        unsigned x = g0 + g1;
        int lane = tid & 63;
#pragma unroll
        for (int off = 1; off < 64; off <<= 1) {
            unsigned y = __shfl_up(x, off, 64);
            if (lane >= off) x += y;
        }
        if (lane == 63) wsum[tid >> 6] = x;
        __syncthreads();
        if (tid < 16) {
            unsigned v = wsum[tid];
#pragma unroll
            for (int off = 1; off < 16; off <<= 1) {
                unsigned y = __shfl_up(v, off, 64);
                if (tid >= off) v += y;
            }
            wsum[tid] = v;
        }
        __syncthreads();
        unsigned basew = (tid >= 64) ? wsum[(tid >> 6) - 1] : 0u;
        unsigned incl  = basew + x;
        unsigned incl0 = incl - g1;
        unsigned K = rem1;
        if (incl0 >= K && incl0 - g0 < K) { sh_bin2 = 2047 - 2 * tid; sh_rem2 = K - (incl0 - g0); }
        if (incl  >= K && incl0     < K) { sh_bin2 = 2046 - 2 * tid; sh_rem2 = K - incl0; }
    }
    __syncthreads();
    unsigned pref22 = (bin1 << 11) | sh_bin2;
    unsigned rem2 = sh_rem2;

    // phase 3: classify
#pragma unroll
    for (int p = 0; p < 4; ++p) {
        unsigned top22 = myk[p] >> 10;
        if (top22 > pref22) {
            unsigned pos = atomicAdd(&sh_cnt, 1u);
            sel_idx[base_sel + pos] = myj[p];
            sel_w[base_sel + pos]   = tanhf(inv_fkey(myk[p]));
        } else if (top22 == pref22) {
            unsigned cp = atomicAdd(&sh_nc, 1u);
            cand[cp] = (unsigned short)myj[p];
        }
    }
    __syncthreads();

    // phase 4: exact rank among candidates (key desc, index asc)
    unsigned nc = sh_nc;
    for (unsigned c = tid; c < nc; c += 1024) {
        int j = cand[c];
        unsigned k32 = keys[j];
        unsigned rank = 0;
        for (unsigned q = 0; q < nc; ++q) {
            int jq = cand[q];
            unsigned kq = keys[jq];
            rank += (kq > k32 || (kq == k32 && jq < j)) ? 1u : 0u;
        }
        if (rank < rem2) {
            unsigned pos = atomicAdd(&sh_cnt, 1u);
            sel_idx[base_sel + pos] = j;
            sel_w[base_sel + pos]   = tanhf(inv_fkey(k32));
        }
    }
}

// ---------- kernel 4: weighted mean of selected rows ----------
__global__ __launch_bounds__(1024) void pool_kernel(
    const float* __restrict__ x_inst, const float* __restrict__ x_data,
    const int* __restrict__ sel_idx, const float* __restrict__ sel_w,
    float* __restrict__ out)
{
    __shared__ int   ridx[64];
    __shared__ float rw[64];
    __shared__ float accs[256];
    int tid   = threadIdx.x;
    int blk   = blockIdx.x;
    int seg   = blk >> 4;
    int chunk = blk & 15;
    int side  = seg >> 4;
    int b     = seg & 15;
    if (tid < 64) {
        ridx[tid] = sel_idx[seg * Kc + chunk * 64 + tid];
        rw[tid]   = sel_w[seg * Kc + chunk * 64 + tid];
    }
    if (tid < 256) accs[tid] = 0.0f;
    __syncthreads();
    const float* x = side ? x_data : x_inst;
    int w = tid >> 6, l = tid & 63;
    float ax = 0.f, ay = 0.f, az = 0.f, aw = 0.f;
#pragma unroll
    for (int r = 0; r < 4; ++r) {
        int   row = ridx[w * 4 + r];
        float wt  = rw[w * 4 + r];
        float4 xv = ((const float4*)(x + ((size_t)(b * NPGc + row)) * Cc))[l];
        ax = fmaf(xv.x, wt, ax); ay = fmaf(xv.y, wt, ay);
        az = fmaf(xv.z, wt, az); aw = fmaf(xv.w, wt, aw);
    }
    atomicAdd(&accs[l * 4 + 0], ax);
    atomicAdd(&accs[l * 4 + 1], ay);
    atomicAdd(&accs[l * 4 + 2], az);
    atomicAdd(&accs[l * 4 + 3], aw);
    __syncthreads();
    if (tid < 256)
        unsafeAtomicAdd(&out[b * 512 + side * 256 + tid], accs[tid] * (1.0f / (float)Kc));
}

extern "C" void kernel_launch(void* const* d_in, const int* in_sizes, int n_in,
                              void* d_out, int out_size, void* d_ws, size_t ws_size,
                              hipStream_t stream) {
    const float* x_inst     = (const float*)d_in[0];
    const float* x_data     = (const float*)d_in[1];
    const float* w_kqv_inst = (const float*)d_in[2];
    const float* b_kqv_inst = (const float*)d_in[3];
    const float* w_kqv_data = (const float*)d_in[4];
    const float* b_kqv_data = (const float*)d_in[5];
    const float* w_out_inst = (const float*)d_in[6];
    const float* b_out_inst = (const float*)d_in[7];
    const float* w_out_data = (const float*)d_in[8];
    const float* b_out_data = (const float*)d_in[9];
    const float* krel_w     = (const float*)d_in[10];
    const float* krel_b     = (const float*)d_in[11];
    const float* vrel_w     = (const float*)d_in[12];
    const float* vrel_b     = (const float*)d_in[13];
    const float* p_rel      = (const float*)d_in[14];
    const int*   ei_i2d     = (const int*)d_in[15];
    const int*   ei_d2i     = (const int*)d_in[16];
    const int*   ei_i2i     = (const int*)d_in[17];
    float* out = (float*)d_out;

    // workspace layout (fp32) — same footprint as round 6 (~15.4 MB)
    char* ws = (char*)d_ws;
    float2* kv_i   = (float2*)ws;                        // N
    float2* kv_d   = kv_i + Nc;                          // N
    float*  q_glob = (float*)(kv_d + Nc);                // 2N
    float*  den    = q_glob + 2 * Nc;                    // 2N
    float*  num    = den + 2 * Nc;                       // 2N
    unsigned* bucket_cnt  = (unsigned*)(num + 2 * Nc);   // NBUK
    unsigned* bucket_base = bucket_cnt + NBUK;           // NBUK+1
    unsigned* bucket_fill = bucket_base + NBUK + 1;      // NBUK
    int*      sel_idx     = (int*)(bucket_fill + NBUK);  // 32*K
    float*    sel_w       = (float*)(sel_idx + 32 * Kc); // 32*K
    unsigned* sorted      = (unsigned*)(sel_w + 32 * Kc);// 3E (12.6 MB)

    hipMemsetAsync(bucket_cnt, 0, NBUK * sizeof(unsigned), stream);
    hipMemsetAsync(d_out, 0, (size_t)out_size * sizeof(float), stream);

    // edge path (independent of x): count -> scan -> fill
    count_kernel<<<NCHUNK, 256, 0, stream>>>(ei_i2d, ei_d2i, ei_i2i, bucket_cnt);
    scan_kernel<<<1, NBUK, 0, stream>>>(bucket_cnt, bucket_base, bucket_fill);
    fill_kernel<<<NCHUNK, 256, 0, stream>>>(ei_i2d, ei_d2i, ei_i2i,
                                            bucket_fill, sorted);

    // kqv for both sides: 32 rows per block, 4096 blocks
    kqv_kernel<<<(2 * Nc) / 32, 256, 0, stream>>>(
        x_inst, x_data, w_kqv_inst, b_kqv_inst, w_kqv_data, b_kqv_data,
        kv_i, kv_d, q_glob);

    // per-bucket LDS accumulate: 512 blocks x 512 threads
    bucket_accum_kernel<<<NBUK, 512, 0, stream>>>(
        bucket_base, sorted,
        krel_w, krel_b, vrel_w, vrel_b, p_rel,
        kv_i, kv_d, q_glob, den, num);

    // score + top-K select
    select_kernel<<<32, 1024, 0, stream>>>(
        den, num, w_out_inst, b_out_inst, w_out_data, b_out_data,
        sel_idx, sel_w);

    // pooled weighted mean
    pool_kernel<<<512, 1024, 0, stream>>>(x_inst, x_data, sel_idx, sel_w, out);
}